// Round 8
// baseline (187.756 us; speedup 1.0000x reference)
//
#include <hip/hip_runtime.h>
#include <stdint.h>

#define NTOK 8192
#define INF  4096
#define OUTF 4096
#define KDIM 4096

using i32x4  = __attribute__((ext_vector_type(4))) int;
using i32x16 = __attribute__((ext_vector_type(16))) int;

#define GLOAD16(gp, lp) __builtin_amdgcn_global_load_lds( \
    (const __attribute__((address_space(1))) uint32_t*)(gp), \
    (__attribute__((address_space(3))) uint32_t*)(lp), 16, 0, 0)

#define SBARP()  do { __builtin_amdgcn_s_barrier(); __builtin_amdgcn_sched_barrier(0); } while (0)
#define SBARX()  __builtin_amdgcn_s_barrier()
#define VMCNT4() do { asm volatile("s_waitcnt vmcnt(4)" ::: "memory"); __builtin_amdgcn_sched_barrier(0); } while (0)
#define VMCNT0() do { asm volatile("s_waitcnt vmcnt(0)" ::: "memory"); __builtin_amdgcn_sched_barrier(0); } while (0)

// ---------------- pack pass: fp32 -> int8 sign (+1 / -1) --------------------
__global__ void pack_i8(const float* __restrict__ x, const float* __restrict__ w,
                        char* __restrict__ xp, char* __restrict__ wp,
                        int gx, int gtot) {
    int gtid = blockIdx.x * blockDim.x + threadIdx.x;
    int nthr = gridDim.x * blockDim.x;
    for (int g = gtid; g < gtot; g += nthr) {
        const float* src;
        char* dst;
        int gi;
        if (g < gx) { src = x; dst = xp; gi = g; }
        else        { src = w; dst = wp; gi = g - gx; }
        const float4* s4 = reinterpret_cast<const float4*>(src + (size_t)gi * 16);
        int words[4];
#pragma unroll
        for (int q = 0; q < 4; ++q) {
            float4 v = s4[q];
            int b0 = (v.x < 0.0f) ? 0xFF : 0x01;
            int b1 = (v.y < 0.0f) ? 0xFF : 0x01;
            int b2 = (v.z < 0.0f) ? 0xFF : 0x01;
            int b3 = (v.w < 0.0f) ? 0xFF : 0x01;
            words[q] = b0 | (b1 << 8) | (b2 << 16) | (b3 << 24);
        }
        int4 o = make_int4(words[0], words[1], words[2], words[3]);
        *reinterpret_cast<int4*>(dst + (size_t)gi * 16) = o;
    }
}

// ======== shared geometry helpers (256 blocks per half, 8 XCDs) =============
// orig&7 = XCD; chunk = 2 row-panels x 16 col-panels, 2 blocks share col-tile.
__device__ __forceinline__ void half_swizzle(int orig, int rowBase,
                                             int& row0, int& col0) {
    const int wgid  = ((orig & 7) << 5) | (orig >> 3);
    const int chunk = wgid >> 5;                 // 0..7
    const int c     = wgid & 31;                 // 0..31
    const int tyi   = (chunk << 1) | (c & 1);    // 0..15
    const int txi   = c >> 1;                    // 0..15
    row0 = rowBase + tyi * 256;
    col0 = txi * 256;
}

// ---------------- variant A (control): 16x16x64, R7 4-phase core ------------
__global__ __launch_bounds__(512, 2) void bgemm_i8_4ph(
        const char*  __restrict__ Xp, const char* __restrict__ Wp,
        const float* __restrict__ bias, float* __restrict__ out, int rowBase)
{
    __shared__ __align__(16) char As[2][32768];
    __shared__ __align__(16) char Bs[2][32768];

    const int tid  = threadIdx.x;
    const int lane = tid & 63;
    const int wid  = tid >> 6;
    const int wr   = wid >> 2;
    const int wc   = wid & 3;
    const int cl   = lane & 15;
    const int rg   = lane >> 4;

    int row0, col0;
    half_swizzle(blockIdx.x, rowBase, row0, col0);

    const int rr     = tid >> 3;
    const int colOff = ((tid & 7) << 4) ^ ((rr & 7) << 4);
    const char* gA = Xp + (size_t)(row0 + rr) * KDIM + colOff;
    const char* gB = Wp + (size_t)(col0 + rr) * KDIM + colOff;
    const int d0 = tid * 16;

#define STGF(arr, p, g, ktB) do { \
    GLOAD16((g) + (size_t)0   * KDIM + (ktB), &arr[p][d0]); \
    GLOAD16((g) + (size_t)64  * KDIM + (ktB), &arr[p][8192 + d0]); \
    GLOAD16((g) + (size_t)128 * KDIM + (ktB), &arr[p][16384 + d0]); \
    GLOAD16((g) + (size_t)192 * KDIM + (ktB), &arr[p][24576 + d0]); \
} while (0)

    const int aRow = (wr * 128 + cl) * 128;
    const int bRow = (wc * 64 + cl) * 128;
    const int kq0  = (rg << 4) ^ ((cl & 7) << 4);
    const int kq1  = kq0 ^ 64;

    i32x4 acc[8][4];
#pragma unroll
    for (int m = 0; m < 8; ++m)
#pragma unroll
        for (int n = 0; n < 4; ++n)
#pragma unroll
            for (int j = 0; j < 4; ++j) acc[m][n][j] = 0;

    i32x4 af[4][2], bf[4][2];

#define LDA(p, MH) do { \
    _Pragma("unroll") for (int m = 0; m < 4; ++m) { \
        af[m][0] = *reinterpret_cast<const i32x4*>(&As[p][aRow + ((MH) * 4 + m) * 2048 + kq0]); \
        af[m][1] = *reinterpret_cast<const i32x4*>(&As[p][aRow + ((MH) * 4 + m) * 2048 + kq1]); \
    } } while (0)
#define LDBALL(p) do { \
    _Pragma("unroll") for (int n = 0; n < 4; ++n) { \
        bf[n][0] = *reinterpret_cast<const i32x4*>(&Bs[p][bRow + (n) * 2048 + kq0]); \
        bf[n][1] = *reinterpret_cast<const i32x4*>(&Bs[p][bRow + (n) * 2048 + kq1]); \
    } } while (0)
#define MMALL(MH) do { \
    __builtin_amdgcn_s_setprio(1); \
    _Pragma("unroll") for (int m = 0; m < 4; ++m) \
    _Pragma("unroll") for (int n = 0; n < 4; ++n) \
    _Pragma("unroll") for (int kk = 0; kk < 2; ++kk) \
        acc[(MH) * 4 + m][n] = __builtin_amdgcn_mfma_i32_16x16x64_i8( \
            af[m][kk], bf[n][kk], acc[(MH) * 4 + m][n], 0, 0, 0); \
    __builtin_amdgcn_s_setprio(0); \
} while (0)

    STGF(As, 0, gA, 0);
    STGF(Bs, 0, gB, 0);
    STGF(Bs, 1, gB, 128);
    VMCNT4();
    SBARX();

    int kb = 0;
#pragma unroll 1
    for (int i = 0; i < 15; ++i, kb += 256) {
        LDA(0, 0); LDBALL(0);
        STGF(As, 1, gA, kb + 128);
        SBARP(); MMALL(0); SBARX();
        LDA(0, 1);
        STGF(Bs, 0, gB, kb + 256);
        SBARP(); MMALL(1);
        VMCNT4(); SBARX();
        LDA(1, 0); LDBALL(1);
        STGF(As, 0, gA, kb + 256);
        SBARP(); MMALL(0); SBARX();
        LDA(1, 1);
        STGF(Bs, 1, gB, kb + 384);
        SBARP(); MMALL(1);
        VMCNT4(); SBARX();
    }

    STGF(As, 1, gA, 3968);
    VMCNT0();
    SBARX();
    LDA(0, 0); LDBALL(0); MMALL(0);
    LDA(0, 1);            MMALL(1);
    LDA(1, 0); LDBALL(1); MMALL(0);
    LDA(1, 1);            MMALL(1);

    float bv[4];
#pragma unroll
    for (int n = 0; n < 4; ++n) bv[n] = bias[col0 + wc * 64 + n * 16 + cl];

#pragma unroll
    for (int m = 0; m < 8; ++m) {
        int rowbase = row0 + wr * 128 + m * 16 + rg * 4;
#pragma unroll
        for (int j = 0; j < 4; ++j) {
            size_t rb = (size_t)(rowbase + j) * OUTF;
#pragma unroll
            for (int n = 0; n < 4; ++n) {
                int col = col0 + wc * 64 + n * 16 + cl;
                out[rb + col] = (float)acc[m][n][j] + bv[n];
            }
        }
    }
#undef STGF
#undef LDA
#undef LDBALL
#undef MMALL
}

// ---------------- variant B: 32x32x32 i8, same schedule ---------------------
// A/B frag: row=lane&31, k-bytes=(lane>>5)*16 within each K=32 step.
// C/D: col=lane&31, row=(reg&3)+8*(reg>>2)+4*(lane>>5)  [HW-verified layout].
__global__ __launch_bounds__(512, 2) void bgemm_i8_4ph_32(
        const char*  __restrict__ Xp, const char* __restrict__ Wp,
        const float* __restrict__ bias, float* __restrict__ out, int rowBase)
{
    __shared__ __align__(16) char As[2][32768];
    __shared__ __align__(16) char Bs[2][32768];

    const int tid  = threadIdx.x;
    const int lane = tid & 63;
    const int wid  = tid >> 6;
    const int wr   = wid >> 2;          // 0..1 (128-row half)
    const int wc   = wid & 3;           // 0..3 (64-col quarter)
    const int al   = lane & 31;
    const int hk   = lane >> 5;         // k-half within 32B k-step

    int row0, col0;
    half_swizzle(blockIdx.x, rowBase, row0, col0);

    const int rr     = tid >> 3;
    const int colOff = ((tid & 7) << 4) ^ ((rr & 7) << 4);
    const char* gA = Xp + (size_t)(row0 + rr) * KDIM + colOff;
    const char* gB = Wp + (size_t)(col0 + rr) * KDIM + colOff;
    const int d0 = tid * 16;

#define STGF(arr, p, g, ktB) do { \
    GLOAD16((g) + (size_t)0   * KDIM + (ktB), &arr[p][d0]); \
    GLOAD16((g) + (size_t)64  * KDIM + (ktB), &arr[p][8192 + d0]); \
    GLOAD16((g) + (size_t)128 * KDIM + (ktB), &arr[p][16384 + d0]); \
    GLOAD16((g) + (size_t)192 * KDIM + (ktB), &arr[p][24576 + d0]); \
} while (0)

    // read addressing: row*128 + ((slot ^ (row&7))<<4), slot = ks*2 + hk
    const int sx = al & 7;              // row&7 == al&7 (bases are mult. of 32)
    const int aB0 = (wr * 128 + al) * 128;   // + mt*32*128
    const int bB0 = (wc * 64 + al) * 128;    // + nt*32*128

    i32x16 acc[4][2];
#pragma unroll
    for (int m = 0; m < 4; ++m)
#pragma unroll
        for (int n = 0; n < 2; ++n)
#pragma unroll
            for (int j = 0; j < 16; ++j) acc[m][n][j] = 0;

    i32x4 af[8], bf[2][4];

#define LDA32(p, MH) do { \
    _Pragma("unroll") for (int m2 = 0; m2 < 2; ++m2) \
    _Pragma("unroll") for (int ks = 0; ks < 4; ++ks) \
        af[m2 * 4 + ks] = *reinterpret_cast<const i32x4*>( \
            &As[p][aB0 + ((MH) * 2 + m2) * 4096 + ((((ks << 1) | hk) ^ sx) << 4)]); \
    } while (0)
#define LDB32(p) do { \
    _Pragma("unroll") for (int n = 0; n < 2; ++n) \
    _Pragma("unroll") for (int ks = 0; ks < 4; ++ks) \
        bf[n][ks] = *reinterpret_cast<const i32x4*>( \
            &Bs[p][bB0 + (n) * 4096 + ((((ks << 1) | hk) ^ sx) << 4)]); \
    } while (0)
#define MM32(MH) do { \
    __builtin_amdgcn_s_setprio(1); \
    _Pragma("unroll") for (int m2 = 0; m2 < 2; ++m2) \
    _Pragma("unroll") for (int n = 0; n < 2; ++n) \
    _Pragma("unroll") for (int ks = 0; ks < 4; ++ks) \
        acc[(MH) * 2 + m2][n] = __builtin_amdgcn_mfma_i32_32x32x32_i8( \
            af[m2 * 4 + ks], bf[n][ks], acc[(MH) * 2 + m2][n], 0, 0, 0); \
    __builtin_amdgcn_s_setprio(0); \
} while (0)

    STGF(As, 0, gA, 0);
    STGF(Bs, 0, gB, 0);
    STGF(Bs, 1, gB, 128);
    VMCNT4();
    SBARX();

    int kb = 0;
#pragma unroll 1
    for (int i = 0; i < 15; ++i, kb += 256) {
        LDA32(0, 0); LDB32(0);
        STGF(As, 1, gA, kb + 128);
        SBARP(); MM32(0); SBARX();
        LDA32(0, 1);
        STGF(Bs, 0, gB, kb + 256);
        SBARP(); MM32(1);
        VMCNT4(); SBARX();
        LDA32(1, 0); LDB32(1);
        STGF(As, 0, gA, kb + 256);
        SBARP(); MM32(0); SBARX();
        LDA32(1, 1);
        STGF(Bs, 1, gB, kb + 384);
        SBARP(); MM32(1);
        VMCNT4(); SBARX();
    }

    STGF(As, 1, gA, 3968);
    VMCNT0();
    SBARX();
    LDA32(0, 0); LDB32(0); MM32(0);
    LDA32(0, 1);           MM32(1);
    LDA32(1, 0); LDB32(1); MM32(0);
    LDA32(1, 1);           MM32(1);

    // C write: col=lane&31, row=(reg&3)+8*(reg>>2)+4*hk
    float bv[2];
#pragma unroll
    for (int n = 0; n < 2; ++n) bv[n] = bias[col0 + wc * 64 + n * 32 + al];

#pragma unroll
    for (int m = 0; m < 4; ++m) {
        int rowb = row0 + wr * 128 + m * 32 + hk * 4;
#pragma unroll
        for (int reg = 0; reg < 16; ++reg) {
            int r = rowb + (reg & 3) + 8 * (reg >> 2);
            size_t rb = (size_t)r * OUTF;
#pragma unroll
            for (int n = 0; n < 2; ++n) {
                int col = col0 + wc * 64 + n * 32 + al;
                out[rb + col] = (float)acc[m][n][reg] + bv[n];
            }
        }
    }
#undef STGF
#undef LDA32
#undef LDB32
#undef MM32
}

// ================= fallback (round-1 popcount path, known-good) =============
#define KW   64
#define LSTRIDE 66

__global__ void pack_both_fb(const float* __restrict__ x, const float* __restrict__ w,
                             uint64_t* __restrict__ xp, uint64_t* __restrict__ wp,
                             int nx, int ntot) {
    int gtid  = blockIdx.x * blockDim.x + threadIdx.x;
    int lane  = threadIdx.x & 63;
    int wave  = gtid >> 6;
    int nwaves = (gridDim.x * blockDim.x) >> 6;
    for (int q = wave; q < ntot; q += nwaves) {
        const float* src; uint64_t* dst; int qi;
        if (q < nx) { src = x; dst = xp; qi = q; }
        else        { src = w; dst = wp; qi = q - nx; }
        float v = src[(size_t)qi * 64 + lane];
        unsigned long long m = __ballot(v < 0.0f);
        if (lane == 0) dst[qi] = (uint64_t)m;
    }
}

__global__ __launch_bounds__(512, 2) void bgemm_popc_fb(
        const uint64_t* __restrict__ xp, const uint64_t* __restrict__ wp,
        const float* __restrict__ bias, float* __restrict__ out)
{
    __shared__ uint64_t xs[128 * LSTRIDE];
    __shared__ uint64_t ws[128 * LSTRIDE];
    const int tid  = threadIdx.x;
    const int row0 = blockIdx.y * 128;
    const int col0 = blockIdx.x * 128;
    {
        const uint64_t* xg = xp + (size_t)row0 * KW;
        const uint64_t* wg = wp + (size_t)col0 * KW;
#pragma unroll
        for (int m = 0; m < 8; ++m) {
            int q = (m * 512 + tid) * 2;
            int r = q >> 6;
            int k = q & 63;
            ulonglong2 vx = *reinterpret_cast<const ulonglong2*>(xg + q);
            xs[r * LSTRIDE + k] = vx.x; xs[r * LSTRIDE + k + 1] = vx.y;
            ulonglong2 vw = *reinterpret_cast<const ulonglong2*>(wg + q);
            ws[r * LSTRIDE + k] = vw.x; ws[r * LSTRIDE + k + 1] = vw.y;
        }
    }
    __syncthreads();
    const int tx = tid & 15;
    const int ty = tid >> 4;
    int acc[4][8];
#pragma unroll
    for (int i = 0; i < 4; ++i)
#pragma unroll
        for (int j = 0; j < 8; ++j) acc[i][j] = 0;
    const uint64_t* xrow = xs + ty * 4 * LSTRIDE;
    const uint64_t* wrow = ws + tx * LSTRIDE;
#pragma unroll 4
    for (int kk = 0; kk < KW; kk += 2) {
        ulonglong2 a[4]; ulonglong2 b[8];
#pragma unroll
        for (int i = 0; i < 4; ++i)
            a[i] = *reinterpret_cast<const ulonglong2*>(xrow + i * LSTRIDE + kk);
#pragma unroll
        for (int j = 0; j < 8; ++j)
            b[j] = *reinterpret_cast<const ulonglong2*>(wrow + j * 16 * LSTRIDE + kk);
#pragma unroll
        for (int i = 0; i < 4; ++i)
#pragma unroll
            for (int j = 0; j < 8; ++j)
                acc[i][j] += __builtin_popcountll(a[i].x ^ b[j].x)
                           + __builtin_popcountll(a[i].y ^ b[j].y);
    }
    float bcol[8];
#pragma unroll
    for (int j = 0; j < 8; ++j) bcol[j] = bias[col0 + tx + 16 * j];
#pragma unroll
    for (int i = 0; i < 4; ++i) {
        size_t r = (size_t)(row0 + ty * 4 + i);
#pragma unroll
        for (int j = 0; j < 8; ++j) {
            int c = col0 + tx + 16 * j;
            out[r * OUTF + c] = (float)(INF - 2 * acc[i][j]) + bcol[j];
        }
    }
}
// ============================================================================

extern "C" void kernel_launch(void* const* d_in, const int* in_sizes, int n_in,
                              void* d_out, int out_size, void* d_ws, size_t ws_size,
                              hipStream_t stream) {
    const float* x    = (const float*)d_in[0];
    const float* w    = (const float*)d_in[1];
    const float* bias = (const float*)d_in[2];
    float* out = (float*)d_out;

    const size_t need = (size_t)NTOK * KDIM + (size_t)OUTF * KDIM; // 50.3 MB
    if (ws_size >= need) {
        char* xp = (char*)d_ws;
        char* wp = xp + (size_t)NTOK * KDIM;
        const int gx   = NTOK * KDIM / 16;
        const int gtot = gx + OUTF * KDIM / 16;
        pack_i8<<<2048, 256, 0, stream>>>(x, w, xp, wp, gx, gtot);
        // A/B split: control (16x16x64) on rows 0..4095, 32x32x32 on 4096..8191
        bgemm_i8_4ph<<<256, 512, 0, stream>>>(xp, wp, bias, out, 0);
        bgemm_i8_4ph_32<<<256, 512, 0, stream>>>(xp, wp, bias, out, 4096);
    } else {
        uint64_t* xp = (uint64_t*)d_ws;
        uint64_t* wp = xp + (size_t)NTOK * KW;
        const int nx   = NTOK * KW;
        const int ntot = nx + OUTF * KW;
        pack_both_fb<<<2048, 256, 0, stream>>>(x, w, xp, wp, nx, ntot);
        dim3 grid(OUTF / 128, NTOK / 128);
        bgemm_popc_fb<<<grid, 512, 0, stream>>>(xp, wp, bias, out);
    }
}

// Round 9
// 178.075 us; speedup vs baseline: 1.0544x; 1.0544x over previous
//
#include <hip/hip_runtime.h>
#include <stdint.h>

#define NTOK 8192
#define INF  4096
#define OUTF 4096
#define KDIM 4096
#define KB4  2048   // packed fp4 row bytes (2 elems/byte)

using i32x4 = __attribute__((ext_vector_type(4))) int;
using i32x8 = __attribute__((ext_vector_type(8))) int;
using f32x4 = __attribute__((ext_vector_type(4))) float;

#if __has_builtin(__builtin_amdgcn_mfma_scale_f32_16x16x128_f8f6f4)
#define HAVE_FP4 1
#else
#define HAVE_FP4 0
#endif

#define GLOAD16(gp, lp) __builtin_amdgcn_global_load_lds( \
    (const __attribute__((address_space(1))) uint32_t*)(gp), \
    (__attribute__((address_space(3))) uint32_t*)(lp), 16, 0, 0)

#define SBARP()  do { __builtin_amdgcn_s_barrier(); __builtin_amdgcn_sched_barrier(0); } while (0)
#define SBARX()  __builtin_amdgcn_s_barrier()
#define VMCNT4() do { asm volatile("s_waitcnt vmcnt(4)" ::: "memory"); __builtin_amdgcn_sched_barrier(0); } while (0)
#define VMCNT0() do { asm volatile("s_waitcnt vmcnt(0)" ::: "memory"); __builtin_amdgcn_sched_barrier(0); } while (0)

// full-grid XCD swizzle (512 blocks, 8 XCDs): chunk = 4 row-panels x 16 col,
// column-major within chunk (4 consecutive blocks share a B col-panel).
__device__ __forceinline__ void full_swizzle(int orig, int& row0, int& col0) {
    const int wgid  = ((orig & 7) << 6) | (orig >> 3);
    const int chunk = wgid >> 6;
    const int c     = wgid & 63;
    row0 = ((chunk << 2) | (c & 3)) * 256;
    col0 = (c >> 2) * 256;
}

// ---------------- pack pass: fp32 -> fp4 e2m1 sign (+1 = 0x2 / -1 = 0xA) ----
// 32 floats -> 16 bytes per thread; low nibble = even element.
__global__ void pack_fp4(const float* __restrict__ x, const float* __restrict__ w,
                         char* __restrict__ xp, char* __restrict__ wp,
                         int gx, int gtot) {
    int gtid = blockIdx.x * blockDim.x + threadIdx.x;
    int nthr = gridDim.x * blockDim.x;
    for (int g = gtid; g < gtot; g += nthr) {
        const float* src;
        char* dst;
        int gi;
        if (g < gx) { src = x; dst = xp; gi = g; }
        else        { src = w; dst = wp; gi = g - gx; }
        const float4* s4 = reinterpret_cast<const float4*>(src + (size_t)gi * 32);
        unsigned int words[4];
#pragma unroll
        for (int wd = 0; wd < 4; ++wd) {
            float4 va = s4[wd * 2];
            float4 vb = s4[wd * 2 + 1];
            unsigned int b0 = (0x2u + ((va.x < 0.0f) ? 8u : 0u)) | ((0x2u + ((va.y < 0.0f) ? 8u : 0u)) << 4);
            unsigned int b1 = (0x2u + ((va.z < 0.0f) ? 8u : 0u)) | ((0x2u + ((va.w < 0.0f) ? 8u : 0u)) << 4);
            unsigned int b2 = (0x2u + ((vb.x < 0.0f) ? 8u : 0u)) | ((0x2u + ((vb.y < 0.0f) ? 8u : 0u)) << 4);
            unsigned int b3 = (0x2u + ((vb.z < 0.0f) ? 8u : 0u)) | ((0x2u + ((vb.w < 0.0f) ? 8u : 0u)) << 4);
            words[wd] = b0 | (b1 << 8) | (b2 << 16) | (b3 << 24);
        }
        uint4 o = make_uint4(words[0], words[1], words[2], words[3]);
        *reinterpret_cast<uint4*>(dst + (size_t)gi * 16) = o;
    }
}

#if HAVE_FP4
// ---------------- MX-FP4 MFMA GEMM, 256x256, 4-phase (R7 schedule) ----------
// Identical staging/swizzle/ledger to the verified i8 4-phase kernel; rows are
// 128 B = 256 fp4 elems = one K-tile (2 x K128 MFMA). 16 K-tiles total.
// Scales fixed at 1.0 (E8M0 0x7F) -> exact +/-1 arithmetic, f32 accum.
__global__ __launch_bounds__(512, 2) void bgemm_fp4(
        const char*  __restrict__ Xp,   // [NTOK][KB4] fp4-packed signs
        const char*  __restrict__ Wp,   // [OUTF][KB4]
        const float* __restrict__ bias, // [OUTF]
        float*       __restrict__ out)  // [NTOK][OUTF]
{
    __shared__ __align__(16) char As[2][32768];
    __shared__ __align__(16) char Bs[2][32768];

    const int tid  = threadIdx.x;
    const int lane = tid & 63;
    const int wid  = tid >> 6;
    const int wr   = wid >> 2;          // 0..1 (128-row half)
    const int wc   = wid & 3;           // 0..3 (64-col quarter)
    const int cl   = lane & 15;
    const int rg   = lane >> 4;

    int row0, col0;
    full_swizzle(blockIdx.x, row0, col0);

    const int rr     = tid >> 3;                       // 0..63
    const int colOff = ((tid & 7) << 4) ^ ((rr & 7) << 4);
    const char* gA = Xp + (size_t)(row0 + rr) * KB4 + colOff;
    const char* gB = Wp + (size_t)(col0 + rr) * KB4 + colOff;
    const int d0 = tid * 16;

#define STGF(arr, p, g, ktB) do { \
    GLOAD16((g) + (size_t)0   * KB4 + (ktB), &arr[p][d0]); \
    GLOAD16((g) + (size_t)64  * KB4 + (ktB), &arr[p][8192 + d0]); \
    GLOAD16((g) + (size_t)128 * KB4 + (ktB), &arr[p][16384 + d0]); \
    GLOAD16((g) + (size_t)192 * KB4 + (ktB), &arr[p][24576 + d0]); \
} while (0)

    const int aRow = (wr * 128 + cl) * 128;
    const int bRow = (wc * 64 + cl) * 128;
    const int kq0  = (rg << 4) ^ ((cl & 7) << 4);
    const int kq1  = kq0 ^ 64;

    f32x4 acc[8][4];
#pragma unroll
    for (int m = 0; m < 8; ++m)
#pragma unroll
        for (int n = 0; n < 4; ++n)
#pragma unroll
            for (int j = 0; j < 4; ++j) acc[m][n][j] = 0.0f;

    i32x4 af[4][2], bf[4][2];

#define LDA(p, MH) do { \
    _Pragma("unroll") for (int m = 0; m < 4; ++m) { \
        af[m][0] = *reinterpret_cast<const i32x4*>(&As[p][aRow + ((MH) * 4 + m) * 2048 + kq0]); \
        af[m][1] = *reinterpret_cast<const i32x4*>(&As[p][aRow + ((MH) * 4 + m) * 2048 + kq1]); \
    } } while (0)
#define LDBALL(p) do { \
    _Pragma("unroll") for (int n = 0; n < 4; ++n) { \
        bf[n][0] = *reinterpret_cast<const i32x4*>(&Bs[p][bRow + (n) * 2048 + kq0]); \
        bf[n][1] = *reinterpret_cast<const i32x4*>(&Bs[p][bRow + (n) * 2048 + kq1]); \
    } } while (0)
// kk outer so consecutive MFMAs hit different acc registers.
#define MMALL(MH) do { \
    __builtin_amdgcn_s_setprio(1); \
    _Pragma("unroll") for (int kk = 0; kk < 2; ++kk) \
    _Pragma("unroll") for (int m = 0; m < 4; ++m) \
    _Pragma("unroll") for (int n = 0; n < 4; ++n) { \
        i32x8 a8 = {af[m][kk][0], af[m][kk][1], af[m][kk][2], af[m][kk][3], 0, 0, 0, 0}; \
        i32x8 b8 = {bf[n][kk][0], bf[n][kk][1], bf[n][kk][2], bf[n][kk][3], 0, 0, 0, 0}; \
        acc[(MH) * 4 + m][n] = __builtin_amdgcn_mfma_scale_f32_16x16x128_f8f6f4( \
            a8, b8, acc[(MH) * 4 + m][n], 4, 4, 0, 0x7F7F7F7F, 0, 0x7F7F7F7F); \
    } \
    __builtin_amdgcn_s_setprio(0); \
} while (0)

    // ---- prologue: tile0 (A,B) + tile1 B = 12 gloads; retire tile0 --------
    STGF(As, 0, gA, 0);
    STGF(Bs, 0, gB, 0);
    STGF(Bs, 1, gB, 128);
    VMCNT4();
    SBARX();

    // ---- main loop: tile 2i (p0) ph0-1, tile 2i+1 (p1) ph2-3 --------------
    int kb = 0;  // = i*256 bytes
#pragma unroll 1
    for (int i = 0; i < 7; ++i, kb += 256) {
        LDA(0, 0); LDBALL(0);
        STGF(As, 1, gA, kb + 128);
        SBARP(); MMALL(0); SBARX();
        LDA(0, 1);
        STGF(Bs, 0, gB, kb + 256);
        SBARP(); MMALL(1);
        VMCNT4(); SBARX();
        LDA(1, 0); LDBALL(1);
        STGF(As, 0, gA, kb + 256);
        SBARP(); MMALL(0); SBARX();
        LDA(1, 1);
        STGF(Bs, 1, gB, kb + 384);
        SBARP(); MMALL(1);
        VMCNT4(); SBARX();
    }

    // ---- epilogue: stage A.p1 (tile15 @1920); drain; compute t14, t15 -----
    STGF(As, 1, gA, 1920);
    VMCNT0();
    SBARX();
    LDA(0, 0); LDBALL(0); MMALL(0);
    LDA(0, 1);            MMALL(1);
    LDA(1, 0); LDBALL(1); MMALL(0);
    LDA(1, 1);            MMALL(1);

    // ---- C write: C/D layout col=lane&15, row=rg*4+j (shape-determined) ---
    float bv[4];
#pragma unroll
    for (int n = 0; n < 4; ++n) bv[n] = bias[col0 + wc * 64 + n * 16 + cl];

#pragma unroll
    for (int m = 0; m < 8; ++m) {
        int rowbase = row0 + wr * 128 + m * 16 + rg * 4;
#pragma unroll
        for (int j = 0; j < 4; ++j) {
            size_t rb = (size_t)(rowbase + j) * OUTF;
#pragma unroll
            for (int n = 0; n < 4; ++n) {
                int col = col0 + wc * 64 + n * 16 + cl;
                out[rb + col] = acc[m][n][j] + bv[n];
            }
        }
    }
#undef STGF
#undef LDA
#undef LDBALL
#undef MMALL
}
#endif  // HAVE_FP4

// ================= i8 path (R7, verified 178 us) — fallback =================
__global__ void pack_i8(const float* __restrict__ x, const float* __restrict__ w,
                        char* __restrict__ xp, char* __restrict__ wp,
                        int gx, int gtot) {
    int gtid = blockIdx.x * blockDim.x + threadIdx.x;
    int nthr = gridDim.x * blockDim.x;
    for (int g = gtid; g < gtot; g += nthr) {
        const float* src;
        char* dst;
        int gi;
        if (g < gx) { src = x; dst = xp; gi = g; }
        else        { src = w; dst = wp; gi = g - gx; }
        const float4* s4 = reinterpret_cast<const float4*>(src + (size_t)gi * 16);
        int words[4];
#pragma unroll
        for (int q = 0; q < 4; ++q) {
            float4 v = s4[q];
            int b0 = (v.x < 0.0f) ? 0xFF : 0x01;
            int b1 = (v.y < 0.0f) ? 0xFF : 0x01;
            int b2 = (v.z < 0.0f) ? 0xFF : 0x01;
            int b3 = (v.w < 0.0f) ? 0xFF : 0x01;
            words[q] = b0 | (b1 << 8) | (b2 << 16) | (b3 << 24);
        }
        int4 o = make_int4(words[0], words[1], words[2], words[3]);
        *reinterpret_cast<int4*>(dst + (size_t)gi * 16) = o;
    }
}

__global__ __launch_bounds__(512, 2) void bgemm_i8_4ph(
        const char*  __restrict__ Xp, const char* __restrict__ Wp,
        const float* __restrict__ bias, float* __restrict__ out)
{
    __shared__ __align__(16) char As[2][32768];
    __shared__ __align__(16) char Bs[2][32768];

    const int tid  = threadIdx.x;
    const int lane = tid & 63;
    const int wid  = tid >> 6;
    const int wr   = wid >> 2;
    const int wc   = wid & 3;
    const int cl   = lane & 15;
    const int rg   = lane >> 4;

    int row0, col0;
    full_swizzle(blockIdx.x, row0, col0);

    const int rr     = tid >> 3;
    const int colOff = ((tid & 7) << 4) ^ ((rr & 7) << 4);
    const char* gA = Xp + (size_t)(row0 + rr) * KDIM + colOff;
    const char* gB = Wp + (size_t)(col0 + rr) * KDIM + colOff;
    const int d0 = tid * 16;

#define STGF(arr, p, g, ktB) do { \
    GLOAD16((g) + (size_t)0   * KDIM + (ktB), &arr[p][d0]); \
    GLOAD16((g) + (size_t)64  * KDIM + (ktB), &arr[p][8192 + d0]); \
    GLOAD16((g) + (size_t)128 * KDIM + (ktB), &arr[p][16384 + d0]); \
    GLOAD16((g) + (size_t)192 * KDIM + (ktB), &arr[p][24576 + d0]); \
} while (0)

    const int aRow = (wr * 128 + cl) * 128;
    const int bRow = (wc * 64 + cl) * 128;
    const int kq0  = (rg << 4) ^ ((cl & 7) << 4);
    const int kq1  = kq0 ^ 64;

    i32x4 acc[8][4];
#pragma unroll
    for (int m = 0; m < 8; ++m)
#pragma unroll
        for (int n = 0; n < 4; ++n)
#pragma unroll
            for (int j = 0; j < 4; ++j) acc[m][n][j] = 0;

    i32x4 af[4][2], bf[4][2];

#define LDA(p, MH) do { \
    _Pragma("unroll") for (int m = 0; m < 4; ++m) { \
        af[m][0] = *reinterpret_cast<const i32x4*>(&As[p][aRow + ((MH) * 4 + m) * 2048 + kq0]); \
        af[m][1] = *reinterpret_cast<const i32x4*>(&As[p][aRow + ((MH) * 4 + m) * 2048 + kq1]); \
    } } while (0)
#define LDBALL(p) do { \
    _Pragma("unroll") for (int n = 0; n < 4; ++n) { \
        bf[n][0] = *reinterpret_cast<const i32x4*>(&Bs[p][bRow + (n) * 2048 + kq0]); \
        bf[n][1] = *reinterpret_cast<const i32x4*>(&Bs[p][bRow + (n) * 2048 + kq1]); \
    } } while (0)
#define MMALL(MH) do { \
    __builtin_amdgcn_s_setprio(1); \
    _Pragma("unroll") for (int m = 0; m < 4; ++m) \
    _Pragma("unroll") for (int n = 0; n < 4; ++n) \
    _Pragma("unroll") for (int kk = 0; kk < 2; ++kk) \
        acc[(MH) * 4 + m][n] = __builtin_amdgcn_mfma_i32_16x16x64_i8( \
            af[m][kk], bf[n][kk], acc[(MH) * 4 + m][n], 0, 0, 0); \
    __builtin_amdgcn_s_setprio(0); \
} while (0)

    STGF(As, 0, gA, 0);
    STGF(Bs, 0, gB, 0);
    STGF(Bs, 1, gB, 128);
    VMCNT4();
    SBARX();

    int kb = 0;
#pragma unroll 1
    for (int i = 0; i < 15; ++i, kb += 256) {
        LDA(0, 0); LDBALL(0);
        STGF(As, 1, gA, kb + 128);
        SBARP(); MMALL(0); SBARX();
        LDA(0, 1);
        STGF(Bs, 0, gB, kb + 256);
        SBARP(); MMALL(1);
        VMCNT4(); SBARX();
        LDA(1, 0); LDBALL(1);
        STGF(As, 0, gA, kb + 256);
        SBARP(); MMALL(0); SBARX();
        LDA(1, 1);
        STGF(Bs, 1, gB, kb + 384);
        SBARP(); MMALL(1);
        VMCNT4(); SBARX();
    }

    STGF(As, 1, gA, 3968);
    VMCNT0();
    SBARX();
    LDA(0, 0); LDBALL(0); MMALL(0);
    LDA(0, 1);            MMALL(1);
    LDA(1, 0); LDBALL(1); MMALL(0);
    LDA(1, 1);            MMALL(1);

    float bv[4];
#pragma unroll
    for (int n = 0; n < 4; ++n) bv[n] = bias[col0 + wc * 64 + n * 16 + cl];

#pragma unroll
    for (int m = 0; m < 8; ++m) {
        int rowbase = row0 + wr * 128 + m * 16 + rg * 4;
#pragma unroll
        for (int j = 0; j < 4; ++j) {
            size_t rb = (size_t)(rowbase + j) * OUTF;
#pragma unroll
            for (int n = 0; n < 4; ++n) {
                int col = col0 + wc * 64 + n * 16 + cl;
                out[rb + col] = (float)acc[m][n][j] + bv[n];
            }
        }
    }
#undef STGF
#undef LDA
#undef LDBALL
#undef MMALL
}

// ================= popcount fallback (round-1, known-good) ==================
#define KW   64
#define LSTRIDE 66

__global__ void pack_both_fb(const float* __restrict__ x, const float* __restrict__ w,
                             uint64_t* __restrict__ xp, uint64_t* __restrict__ wp,
                             int nx, int ntot) {
    int gtid  = blockIdx.x * blockDim.x + threadIdx.x;
    int lane  = threadIdx.x & 63;
    int wave  = gtid >> 6;
    int nwaves = (gridDim.x * blockDim.x) >> 6;
    for (int q = wave; q < ntot; q += nwaves) {
        const float* src; uint64_t* dst; int qi;
        if (q < nx) { src = x; dst = xp; qi = q; }
        else        { src = w; dst = wp; qi = q - nx; }
        float v = src[(size_t)qi * 64 + lane];
        unsigned long long m = __ballot(v < 0.0f);
        if (lane == 0) dst[qi] = (uint64_t)m;
    }
}

__global__ __launch_bounds__(512, 2) void bgemm_popc_fb(
        const uint64_t* __restrict__ xp, const uint64_t* __restrict__ wp,
        const float* __restrict__ bias, float* __restrict__ out)
{
    __shared__ uint64_t xs[128 * LSTRIDE];
    __shared__ uint64_t ws[128 * LSTRIDE];
    const int tid  = threadIdx.x;
    const int row0 = blockIdx.y * 128;
    const int col0 = blockIdx.x * 128;
    {
        const uint64_t* xg = xp + (size_t)row0 * KW;
        const uint64_t* wg = wp + (size_t)col0 * KW;
#pragma unroll
        for (int m = 0; m < 8; ++m) {
            int q = (m * 512 + tid) * 2;
            int r = q >> 6;
            int k = q & 63;
            ulonglong2 vx = *reinterpret_cast<const ulonglong2*>(xg + q);
            xs[r * LSTRIDE + k] = vx.x; xs[r * LSTRIDE + k + 1] = vx.y;
            ulonglong2 vw = *reinterpret_cast<const ulonglong2*>(wg + q);
            ws[r * LSTRIDE + k] = vw.x; ws[r * LSTRIDE + k + 1] = vw.y;
        }
    }
    __syncthreads();
    const int tx = tid & 15;
    const int ty = tid >> 4;
    int acc[4][8];
#pragma unroll
    for (int i = 0; i < 4; ++i)
#pragma unroll
        for (int j = 0; j < 8; ++j) acc[i][j] = 0;
    const uint64_t* xrow = xs + ty * 4 * LSTRIDE;
    const uint64_t* wrow = ws + tx * LSTRIDE;
#pragma unroll 4
    for (int kk = 0; kk < KW; kk += 2) {
        ulonglong2 a[4]; ulonglong2 b[8];
#pragma unroll
        for (int i = 0; i < 4; ++i)
            a[i] = *reinterpret_cast<const ulonglong2*>(xrow + i * LSTRIDE + kk);
#pragma unroll
        for (int j = 0; j < 8; ++j)
            b[j] = *reinterpret_cast<const ulonglong2*>(wrow + j * 16 * LSTRIDE + kk);
#pragma unroll
        for (int i = 0; i < 4; ++i)
#pragma unroll
            for (int j = 0; j < 8; ++j)
                acc[i][j] += __builtin_popcountll(a[i].x ^ b[j].x)
                           + __builtin_popcountll(a[i].y ^ b[j].y);
    }
    float bcol[8];
#pragma unroll
    for (int j = 0; j < 8; ++j) bcol[j] = bias[col0 + tx + 16 * j];
#pragma unroll
    for (int i = 0; i < 4; ++i) {
        size_t r = (size_t)(row0 + ty * 4 + i);
#pragma unroll
        for (int j = 0; j < 8; ++j) {
            int c = col0 + tx + 16 * j;
            out[r * OUTF + c] = (float)(INF - 2 * acc[i][j]) + bcol[j];
        }
    }
}
// ============================================================================

extern "C" void kernel_launch(void* const* d_in, const int* in_sizes, int n_in,
                              void* d_out, int out_size, void* d_ws, size_t ws_size,
                              hipStream_t stream) {
    const float* x    = (const float*)d_in[0];
    const float* w    = (const float*)d_in[1];
    const float* bias = (const float*)d_in[2];
    float* out = (float*)d_out;

    const size_t need4 = (size_t)NTOK * KB4 + (size_t)OUTF * KB4;   // 25.2 MB
    const size_t need8 = (size_t)NTOK * KDIM + (size_t)OUTF * KDIM; // 50.3 MB

#if HAVE_FP4
    if (ws_size >= need4) {
        char* xp = (char*)d_ws;
        char* wp = xp + (size_t)NTOK * KB4;
        const int gx   = NTOK * KDIM / 32;                // 1048576
        const int gtot = gx + OUTF * KDIM / 32;           // 1572864
        pack_fp4<<<2048, 256, 0, stream>>>(x, w, xp, wp, gx, gtot);
        bgemm_fp4<<<512, 512, 0, stream>>>(xp, wp, bias, out);
        return;
    }
#endif
    if (ws_size >= need8) {
        char* xp = (char*)d_ws;
        char* wp = xp + (size_t)NTOK * KDIM;
        const int gx   = NTOK * KDIM / 16;
        const int gtot = gx + OUTF * KDIM / 16;
        pack_i8<<<2048, 256, 0, stream>>>(x, w, xp, wp, gx, gtot);
        bgemm_i8_4ph<<<512, 512, 0, stream>>>(xp, wp, bias, out);
    } else {
        uint64_t* xp = (uint64_t*)d_ws;
        uint64_t* wp = xp + (size_t)NTOK * KW;
        const int nx   = NTOK * KW;
        const int ntot = nx + OUTF * KW;
        pack_both_fb<<<2048, 256, 0, stream>>>(x, w, xp, wp, nx, ntot);
        dim3 grid(OUTF / 128, NTOK / 128);
        bgemm_popc_fb<<<grid, 512, 0, stream>>>(xp, wp, bias, out);
    }
}

// Round 10
// 131.499 us; speedup vs baseline: 1.4278x; 1.3542x over previous
//
#include <hip/hip_runtime.h>
#include <stdint.h>

#define NTOK 8192
#define INF  4096
#define OUTF 4096
#define KDIM 4096
#define KB4  2048   // packed fp4 row bytes (2 elems/byte)

using i32x4 = __attribute__((ext_vector_type(4))) int;
using i32x8 = __attribute__((ext_vector_type(8))) int;
using f32x4 = __attribute__((ext_vector_type(4))) float;

#define GLOAD16(gp, lp) __builtin_amdgcn_global_load_lds( \
    (const __attribute__((address_space(1))) uint32_t*)(gp), \
    (__attribute__((address_space(3))) uint32_t*)(lp), 16, 0, 0)

#define SBARP()  do { __builtin_amdgcn_s_barrier(); __builtin_amdgcn_sched_barrier(0); } while (0)
#define SBARX()  __builtin_amdgcn_s_barrier()
#define VMCNT4() do { asm volatile("s_waitcnt vmcnt(4)" ::: "memory"); __builtin_amdgcn_sched_barrier(0); } while (0)
#define VMCNT0() do { asm volatile("s_waitcnt vmcnt(0)" ::: "memory"); __builtin_amdgcn_sched_barrier(0); } while (0)

// full-grid XCD swizzle (512 blocks, 8 XCDs): chunk = 4 row-panels x 16 col,
// column-major within chunk (4 consecutive blocks share a B col-panel).
__device__ __forceinline__ void full_swizzle(int orig, int& row0, int& col0) {
    const int wgid  = ((orig & 7) << 6) | (orig >> 3);
    const int chunk = wgid >> 6;
    const int c     = wgid & 63;
    row0 = ((chunk << 2) | (c & 3)) * 256;
    col0 = (c >> 2) * 256;
}

// ---------------- pack pass: fp32 -> fp4 e2m1 sign (+1 = 0x2 / -1 = 0xA) ----
// 32 floats -> 16 bytes per thread; low nibble = even element.
__global__ void pack_fp4(const float* __restrict__ x, const float* __restrict__ w,
                         char* __restrict__ xp, char* __restrict__ wp,
                         int gx, int gtot) {
    int gtid = blockIdx.x * blockDim.x + threadIdx.x;
    int nthr = gridDim.x * blockDim.x;
    for (int g = gtid; g < gtot; g += nthr) {
        const float* src;
        char* dst;
        int gi;
        if (g < gx) { src = x; dst = xp; gi = g; }
        else        { src = w; dst = wp; gi = g - gx; }
        const float4* s4 = reinterpret_cast<const float4*>(src + (size_t)gi * 32);
        unsigned int words[4];
#pragma unroll
        for (int wd = 0; wd < 4; ++wd) {
            float4 va = s4[wd * 2];
            float4 vb = s4[wd * 2 + 1];
            unsigned int b0 = (0x2u + ((va.x < 0.0f) ? 8u : 0u)) | ((0x2u + ((va.y < 0.0f) ? 8u : 0u)) << 4);
            unsigned int b1 = (0x2u + ((va.z < 0.0f) ? 8u : 0u)) | ((0x2u + ((va.w < 0.0f) ? 8u : 0u)) << 4);
            unsigned int b2 = (0x2u + ((vb.x < 0.0f) ? 8u : 0u)) | ((0x2u + ((vb.y < 0.0f) ? 8u : 0u)) << 4);
            unsigned int b3 = (0x2u + ((vb.z < 0.0f) ? 8u : 0u)) | ((0x2u + ((vb.w < 0.0f) ? 8u : 0u)) << 4);
            words[wd] = b0 | (b1 << 8) | (b2 << 16) | (b3 << 24);
        }
        uint4 o = make_uint4(words[0], words[1], words[2], words[3]);
        *reinterpret_cast<uint4*>(dst + (size_t)gi * 16) = o;
    }
}

// ---------------- MX-FP4 MFMA GEMM, 256x256, 4-phase (R7 schedule) ----------
// Identical staging/swizzle/ledger to the verified i8 4-phase kernel; rows are
// 128 B = 256 fp4 elems = one K-tile (2 x K128 MFMA). 16 K-tiles total.
// Scales fixed at 1.0 (E8M0 0x7F) -> exact +/-1 arithmetic, f32 accum.
// FMT code 4 = fp4 for both A (cbsz) and B (blgp).
__global__ __launch_bounds__(512, 2) void bgemm_fp4(
        const char*  __restrict__ Xp,   // [NTOK][KB4] fp4-packed signs
        const char*  __restrict__ Wp,   // [OUTF][KB4]
        const float* __restrict__ bias, // [OUTF]
        float*       __restrict__ out)  // [NTOK][OUTF]
{
    __shared__ __align__(16) char As[2][32768];
    __shared__ __align__(16) char Bs[2][32768];

    const int tid  = threadIdx.x;
    const int lane = tid & 63;
    const int wid  = tid >> 6;
    const int wr   = wid >> 2;          // 0..1 (128-row half)
    const int wc   = wid & 3;           // 0..3 (64-col quarter)
    const int cl   = lane & 15;
    const int rg   = lane >> 4;

    int row0, col0;
    full_swizzle(blockIdx.x, row0, col0);

    const int rr     = tid >> 3;                       // 0..63
    const int colOff = ((tid & 7) << 4) ^ ((rr & 7) << 4);
    const char* gA = Xp + (size_t)(row0 + rr) * KB4 + colOff;
    const char* gB = Wp + (size_t)(col0 + rr) * KB4 + colOff;
    const int d0 = tid * 16;

#define STGF(arr, p, g, ktB) do { \
    GLOAD16((g) + (size_t)0   * KB4 + (ktB), &arr[p][d0]); \
    GLOAD16((g) + (size_t)64  * KB4 + (ktB), &arr[p][8192 + d0]); \
    GLOAD16((g) + (size_t)128 * KB4 + (ktB), &arr[p][16384 + d0]); \
    GLOAD16((g) + (size_t)192 * KB4 + (ktB), &arr[p][24576 + d0]); \
} while (0)

    const int aRow = (wr * 128 + cl) * 128;
    const int bRow = (wc * 64 + cl) * 128;
    const int kq0  = (rg << 4) ^ ((cl & 7) << 4);
    const int kq1  = kq0 ^ 64;

    f32x4 acc[8][4];
#pragma unroll
    for (int m = 0; m < 8; ++m)
#pragma unroll
        for (int n = 0; n < 4; ++n)
#pragma unroll
            for (int j = 0; j < 4; ++j) acc[m][n][j] = 0.0f;

    i32x4 af[4][2], bf[4][2];

#define LDA(p, MH) do { \
    _Pragma("unroll") for (int m = 0; m < 4; ++m) { \
        af[m][0] = *reinterpret_cast<const i32x4*>(&As[p][aRow + ((MH) * 4 + m) * 2048 + kq0]); \
        af[m][1] = *reinterpret_cast<const i32x4*>(&As[p][aRow + ((MH) * 4 + m) * 2048 + kq1]); \
    } } while (0)
#define LDBALL(p) do { \
    _Pragma("unroll") for (int n = 0; n < 4; ++n) { \
        bf[n][0] = *reinterpret_cast<const i32x4*>(&Bs[p][bRow + (n) * 2048 + kq0]); \
        bf[n][1] = *reinterpret_cast<const i32x4*>(&Bs[p][bRow + (n) * 2048 + kq1]); \
    } } while (0)
// kk outer so consecutive MFMAs hit different acc registers.
#define MMALL(MH) do { \
    __builtin_amdgcn_s_setprio(1); \
    _Pragma("unroll") for (int kk = 0; kk < 2; ++kk) \
    _Pragma("unroll") for (int m = 0; m < 4; ++m) \
    _Pragma("unroll") for (int n = 0; n < 4; ++n) { \
        i32x8 a8 = {af[m][kk][0], af[m][kk][1], af[m][kk][2], af[m][kk][3], 0, 0, 0, 0}; \
        i32x8 b8 = {bf[n][kk][0], bf[n][kk][1], bf[n][kk][2], bf[n][kk][3], 0, 0, 0, 0}; \
        acc[(MH) * 4 + m][n] = __builtin_amdgcn_mfma_scale_f32_16x16x128_f8f6f4( \
            a8, b8, acc[(MH) * 4 + m][n], 4, 4, 0, 0x7F7F7F7F, 0, 0x7F7F7F7F); \
    } \
    __builtin_amdgcn_s_setprio(0); \
} while (0)

    // ---- prologue: tile0 (A,B) + tile1 B = 12 gloads; retire tile0 --------
    STGF(As, 0, gA, 0);
    STGF(Bs, 0, gB, 0);
    STGF(Bs, 1, gB, 128);
    VMCNT4();
    SBARX();

    // ---- main loop: tile 2i (p0) ph0-1, tile 2i+1 (p1) ph2-3 --------------
    int kb = 0;  // = i*256 bytes
#pragma unroll 1
    for (int i = 0; i < 7; ++i, kb += 256) {
        LDA(0, 0); LDBALL(0);
        STGF(As, 1, gA, kb + 128);
        SBARP(); MMALL(0); SBARX();
        LDA(0, 1);
        STGF(Bs, 0, gB, kb + 256);
        SBARP(); MMALL(1);
        VMCNT4(); SBARX();
        LDA(1, 0); LDBALL(1);
        STGF(As, 0, gA, kb + 256);
        SBARP(); MMALL(0); SBARX();
        LDA(1, 1);
        STGF(Bs, 1, gB, kb + 384);
        SBARP(); MMALL(1);
        VMCNT4(); SBARX();
    }

    // ---- epilogue: stage A.p1 (tile15 @1920); drain; compute t14, t15 -----
    STGF(As, 1, gA, 1920);
    VMCNT0();
    SBARX();
    LDA(0, 0); LDBALL(0); MMALL(0);
    LDA(0, 1);            MMALL(1);
    LDA(1, 0); LDBALL(1); MMALL(0);
    LDA(1, 1);            MMALL(1);

    // ---- C write: C/D layout col=lane&15, row=rg*4+j (shape-determined) ---
    float bv[4];
#pragma unroll
    for (int n = 0; n < 4; ++n) bv[n] = bias[col0 + wc * 64 + n * 16 + cl];

#pragma unroll
    for (int m = 0; m < 8; ++m) {
        int rowbase = row0 + wr * 128 + m * 16 + rg * 4;
#pragma unroll
        for (int j = 0; j < 4; ++j) {
            size_t rb = (size_t)(rowbase + j) * OUTF;
#pragma unroll
            for (int n = 0; n < 4; ++n) {
                int col = col0 + wc * 64 + n * 16 + cl;
                out[rb + col] = acc[m][n][j] + bv[n];
            }
        }
    }
#undef STGF
#undef LDA
#undef LDBALL
#undef MMALL
}

// ================= i8 path (R7, verified 178 us) — fallback =================
__global__ void pack_i8(const float* __restrict__ x, const float* __restrict__ w,
                        char* __restrict__ xp, char* __restrict__ wp,
                        int gx, int gtot) {
    int gtid = blockIdx.x * blockDim.x + threadIdx.x;
    int nthr = gridDim.x * blockDim.x;
    for (int g = gtid; g < gtot; g += nthr) {
        const float* src;
        char* dst;
        int gi;
        if (g < gx) { src = x; dst = xp; gi = g; }
        else        { src = w; dst = wp; gi = g - gx; }
        const float4* s4 = reinterpret_cast<const float4*>(src + (size_t)gi * 16);
        int words[4];
#pragma unroll
        for (int q = 0; q < 4; ++q) {
            float4 v = s4[q];
            int b0 = (v.x < 0.0f) ? 0xFF : 0x01;
            int b1 = (v.y < 0.0f) ? 0xFF : 0x01;
            int b2 = (v.z < 0.0f) ? 0xFF : 0x01;
            int b3 = (v.w < 0.0f) ? 0xFF : 0x01;
            words[q] = b0 | (b1 << 8) | (b2 << 16) | (b3 << 24);
        }
        int4 o = make_int4(words[0], words[1], words[2], words[3]);
        *reinterpret_cast<int4*>(dst + (size_t)gi * 16) = o;
    }
}

__global__ __launch_bounds__(512, 2) void bgemm_i8_4ph(
        const char*  __restrict__ Xp, const char* __restrict__ Wp,
        const float* __restrict__ bias, float* __restrict__ out)
{
    __shared__ __align__(16) char As[2][32768];
    __shared__ __align__(16) char Bs[2][32768];

    const int tid  = threadIdx.x;
    const int lane = tid & 63;
    const int wid  = tid >> 6;
    const int wr   = wid >> 2;
    const int wc   = wid & 3;
    const int cl   = lane & 15;
    const int rg   = lane >> 4;

    int row0, col0;
    full_swizzle(blockIdx.x, row0, col0);

    const int rr     = tid >> 3;
    const int colOff = ((tid & 7) << 4) ^ ((rr & 7) << 4);
    const char* gA = Xp + (size_t)(row0 + rr) * KDIM + colOff;
    const char* gB = Wp + (size_t)(col0 + rr) * KDIM + colOff;
    const int d0 = tid * 16;

#define STGF(arr, p, g, ktB) do { \
    GLOAD16((g) + (size_t)0   * KDIM + (ktB), &arr[p][d0]); \
    GLOAD16((g) + (size_t)64  * KDIM + (ktB), &arr[p][8192 + d0]); \
    GLOAD16((g) + (size_t)128 * KDIM + (ktB), &arr[p][16384 + d0]); \
    GLOAD16((g) + (size_t)192 * KDIM + (ktB), &arr[p][24576 + d0]); \
} while (0)

    const int aRow = (wr * 128 + cl) * 128;
    const int bRow = (wc * 64 + cl) * 128;
    const int kq0  = (rg << 4) ^ ((cl & 7) << 4);
    const int kq1  = kq0 ^ 64;

    i32x4 acc[8][4];
#pragma unroll
    for (int m = 0; m < 8; ++m)
#pragma unroll
        for (int n = 0; n < 4; ++n)
#pragma unroll
            for (int j = 0; j < 4; ++j) acc[m][n][j] = 0;

    i32x4 af[4][2], bf[4][2];

#define LDA(p, MH) do { \
    _Pragma("unroll") for (int m = 0; m < 4; ++m) { \
        af[m][0] = *reinterpret_cast<const i32x4*>(&As[p][aRow + ((MH) * 4 + m) * 2048 + kq0]); \
        af[m][1] = *reinterpret_cast<const i32x4*>(&As[p][aRow + ((MH) * 4 + m) * 2048 + kq1]); \
    } } while (0)
#define LDBALL(p) do { \
    _Pragma("unroll") for (int n = 0; n < 4; ++n) { \
        bf[n][0] = *reinterpret_cast<const i32x4*>(&Bs[p][bRow + (n) * 2048 + kq0]); \
        bf[n][1] = *reinterpret_cast<const i32x4*>(&Bs[p][bRow + (n) * 2048 + kq1]); \
    } } while (0)
#define MMALL(MH) do { \
    __builtin_amdgcn_s_setprio(1); \
    _Pragma("unroll") for (int m = 0; m < 4; ++m) \
    _Pragma("unroll") for (int n = 0; n < 4; ++n) \
    _Pragma("unroll") for (int kk = 0; kk < 2; ++kk) \
        acc[(MH) * 4 + m][n] = __builtin_amdgcn_mfma_i32_16x16x64_i8( \
            af[m][kk], bf[n][kk], acc[(MH) * 4 + m][n], 0, 0, 0); \
    __builtin_amdgcn_s_setprio(0); \
} while (0)

    STGF(As, 0, gA, 0);
    STGF(Bs, 0, gB, 0);
    STGF(Bs, 1, gB, 128);
    VMCNT4();
    SBARX();

    int kb = 0;
#pragma unroll 1
    for (int i = 0; i < 15; ++i, kb += 256) {
        LDA(0, 0); LDBALL(0);
        STGF(As, 1, gA, kb + 128);
        SBARP(); MMALL(0); SBARX();
        LDA(0, 1);
        STGF(Bs, 0, gB, kb + 256);
        SBARP(); MMALL(1);
        VMCNT4(); SBARX();
        LDA(1, 0); LDBALL(1);
        STGF(As, 0, gA, kb + 256);
        SBARP(); MMALL(0); SBARX();
        LDA(1, 1);
        STGF(Bs, 1, gB, kb + 384);
        SBARP(); MMALL(1);
        VMCNT4(); SBARX();
    }

    STGF(As, 1, gA, 3968);
    VMCNT0();
    SBARX();
    LDA(0, 0); LDBALL(0); MMALL(0);
    LDA(0, 1);            MMALL(1);
    LDA(1, 0); LDBALL(1); MMALL(0);
    LDA(1, 1);            MMALL(1);

    float bv[4];
#pragma unroll
    for (int n = 0; n < 4; ++n) bv[n] = bias[col0 + wc * 64 + n * 16 + cl];

#pragma unroll
    for (int m = 0; m < 8; ++m) {
        int rowbase = row0 + wr * 128 + m * 16 + rg * 4;
#pragma unroll
        for (int j = 0; j < 4; ++j) {
            size_t rb = (size_t)(rowbase + j) * OUTF;
#pragma unroll
            for (int n = 0; n < 4; ++n) {
                int col = col0 + wc * 64 + n * 16 + cl;
                out[rb + col] = (float)acc[m][n][j] + bv[n];
            }
        }
    }
#undef STGF
#undef LDA
#undef LDBALL
#undef MMALL
}

// ================= popcount fallback (round-1, known-good) ==================
#define KW   64
#define LSTRIDE 66

__global__ void pack_both_fb(const float* __restrict__ x, const float* __restrict__ w,
                             uint64_t* __restrict__ xp, uint64_t* __restrict__ wp,
                             int nx, int ntot) {
    int gtid  = blockIdx.x * blockDim.x + threadIdx.x;
    int lane  = threadIdx.x & 63;
    int wave  = gtid >> 6;
    int nwaves = (gridDim.x * blockDim.x) >> 6;
    for (int q = wave; q < ntot; q += nwaves) {
        const float* src; uint64_t* dst; int qi;
        if (q < nx) { src = x; dst = xp; qi = q; }
        else        { src = w; dst = wp; qi = q - nx; }
        float v = src[(size_t)qi * 64 + lane];
        unsigned long long m = __ballot(v < 0.0f);
        if (lane == 0) dst[qi] = (uint64_t)m;
    }
}

__global__ __launch_bounds__(512, 2) void bgemm_popc_fb(
        const uint64_t* __restrict__ xp, const uint64_t* __restrict__ wp,
        const float* __restrict__ bias, float* __restrict__ out)
{
    __shared__ uint64_t xs[128 * LSTRIDE];
    __shared__ uint64_t ws[128 * LSTRIDE];
    const int tid  = threadIdx.x;
    const int row0 = blockIdx.y * 128;
    const int col0 = blockIdx.x * 128;
    {
        const uint64_t* xg = xp + (size_t)row0 * KW;
        const uint64_t* wg = wp + (size_t)col0 * KW;
#pragma unroll
        for (int m = 0; m < 8; ++m) {
            int q = (m * 512 + tid) * 2;
            int r = q >> 6;
            int k = q & 63;
            ulonglong2 vx = *reinterpret_cast<const ulonglong2*>(xg + q);
            xs[r * LSTRIDE + k] = vx.x; xs[r * LSTRIDE + k + 1] = vx.y;
            ulonglong2 vw = *reinterpret_cast<const ulonglong2*>(wg + q);
            ws[r * LSTRIDE + k] = vw.x; ws[r * LSTRIDE + k + 1] = vw.y;
        }
    }
    __syncthreads();
    const int tx = tid & 15;
    const int ty = tid >> 4;
    int acc[4][8];
#pragma unroll
    for (int i = 0; i < 4; ++i)
#pragma unroll
        for (int j = 0; j < 8; ++j) acc[i][j] = 0;
    const uint64_t* xrow = xs + ty * 4 * LSTRIDE;
    const uint64_t* wrow = ws + tx * LSTRIDE;
#pragma unroll 4
    for (int kk = 0; kk < KW; kk += 2) {
        ulonglong2 a[4]; ulonglong2 b[8];
#pragma unroll
        for (int i = 0; i < 4; ++i)
            a[i] = *reinterpret_cast<const ulonglong2*>(xrow + i * LSTRIDE + kk);
#pragma unroll
        for (int j = 0; j < 8; ++j)
            b[j] = *reinterpret_cast<const ulonglong2*>(wrow + j * 16 * LSTRIDE + kk);
#pragma unroll
        for (int i = 0; i < 4; ++i)
#pragma unroll
            for (int j = 0; j < 8; ++j)
                acc[i][j] += __builtin_popcountll(a[i].x ^ b[j].x)
                           + __builtin_popcountll(a[i].y ^ b[j].y);
    }
    float bcol[8];
#pragma unroll
    for (int j = 0; j < 8; ++j) bcol[j] = bias[col0 + tx + 16 * j];
#pragma unroll
    for (int i = 0; i < 4; ++i) {
        size_t r = (size_t)(row0 + ty * 4 + i);
#pragma unroll
        for (int j = 0; j < 8; ++j) {
            int c = col0 + tx + 16 * j;
            out[r * OUTF + c] = (float)(INF - 2 * acc[i][j]) + bcol[j];
        }
    }
}
// ============================================================================

extern "C" void kernel_launch(void* const* d_in, const int* in_sizes, int n_in,
                              void* d_out, int out_size, void* d_ws, size_t ws_size,
                              hipStream_t stream) {
    const float* x    = (const float*)d_in[0];
    const float* w    = (const float*)d_in[1];
    const float* bias = (const float*)d_in[2];
    float* out = (float*)d_out;

    const size_t need4 = (size_t)NTOK * KB4 + (size_t)OUTF * KB4;   // 25.2 MB
    const size_t need8 = (size_t)NTOK * KDIM + (size_t)OUTF * KDIM; // 50.3 MB

    if (ws_size >= need4) {
        char* xp = (char*)d_ws;
        char* wp = xp + (size_t)NTOK * KB4;
        const int gx   = NTOK * KDIM / 32;                // 1048576
        const int gtot = gx + OUTF * KDIM / 32;           // 1572864
        pack_fp4<<<2048, 256, 0, stream>>>(x, w, xp, wp, gx, gtot);
        bgemm_fp4<<<512, 512, 0, stream>>>(xp, wp, bias, out);
    } else if (ws_size >= need8) {
        char* xp = (char*)d_ws;
        char* wp = xp + (size_t)NTOK * KDIM;
        const int gx   = NTOK * KDIM / 16;
        const int gtot = gx + OUTF * KDIM / 16;
        pack_i8<<<2048, 256, 0, stream>>>(x, w, xp, wp, gx, gtot);
        bgemm_i8_4ph<<<512, 512, 0, stream>>>(xp, wp, bias, out);
    } else {
        uint64_t* xp = (uint64_t*)d_ws;
        uint64_t* wp = xp + (size_t)NTOK * KW;
        const int nx   = NTOK * KW;
        const int ntot = nx + OUTF * KW;
        pack_both_fb<<<2048, 256, 0, stream>>>(x, w, xp, wp, nx, ntot);
        dim3 grid(OUTF / 128, NTOK / 128);
        bgemm_popc_fb<<<grid, 512, 0, stream>>>(xp, wp, bias, out);
    }
}

// Round 11
// 131.012 us; speedup vs baseline: 1.4331x; 1.0037x over previous
//
#include <hip/hip_runtime.h>
#include <stdint.h>

#define NTOK 8192
#define INF  4096
#define OUTF 4096
#define KDIM 4096
#define KB4  2048   // packed fp4 row bytes (2 elems/byte)

using i32x4 = __attribute__((ext_vector_type(4))) int;
using i32x8 = __attribute__((ext_vector_type(8))) int;
using f32x4 = __attribute__((ext_vector_type(4))) float;

#define GLOAD16(gp, lp) __builtin_amdgcn_global_load_lds( \
    (const __attribute__((address_space(1))) uint32_t*)(gp), \
    (__attribute__((address_space(3))) uint32_t*)(lp), 16, 0, 0)

// single end-of-phase barrier; sched_barrier pins the ledger (no cross-phase hoist)
#define SBARE()  do { __builtin_amdgcn_s_barrier(); __builtin_amdgcn_sched_barrier(0); } while (0)
#define VMCNT4() do { asm volatile("s_waitcnt vmcnt(4)" ::: "memory"); __builtin_amdgcn_sched_barrier(0); } while (0)
#define VMCNT0() do { asm volatile("s_waitcnt vmcnt(0)" ::: "memory"); __builtin_amdgcn_sched_barrier(0); } while (0)

// full-grid XCD swizzle (512 blocks, 8 XCDs): chunk = 4 row-panels x 16 col,
// column-major within chunk (4 consecutive blocks share a B col-panel).
__device__ __forceinline__ void full_swizzle(int orig, int& row0, int& col0) {
    const int wgid  = ((orig & 7) << 6) | (orig >> 3);
    const int chunk = wgid >> 6;
    const int c     = wgid & 63;
    row0 = ((chunk << 2) | (c & 3)) * 256;
    col0 = (c >> 2) * 256;
}

// ---------------- pack pass v2: lane-contiguous fp32 -> fp4 sign ------------
// One float4 per lane per iter: reads 1 KB/wave/instr (fully coalesced),
// writes ushort/lane (128 B/wave contiguous). elem e -> byte e>>1, low nibble
// = even elem. +1 = 0x2, -1 = 0xA (e2m1).
__global__ void pack_fp4(const float* __restrict__ x, const float* __restrict__ w,
                         char* __restrict__ xp, char* __restrict__ wp,
                         int gx4, int gtot4) {
    int gtid = blockIdx.x * blockDim.x + threadIdx.x;
    int nthr = gridDim.x * blockDim.x;
    for (int g = gtid; g < gtot4; g += nthr) {
        const float4* s;
        uint16_t* d;
        int gi;
        if (g < gx4) { s = (const float4*)x; d = (uint16_t*)xp; gi = g; }
        else         { s = (const float4*)w; d = (uint16_t*)wp; gi = g - gx4; }
        float4 v = s[gi];
        unsigned int n0 = 0x2u | ((v.x < 0.0f) ? 8u : 0u);
        unsigned int n1 = 0x2u | ((v.y < 0.0f) ? 8u : 0u);
        unsigned int n2 = 0x2u | ((v.z < 0.0f) ? 8u : 0u);
        unsigned int n3 = 0x2u | ((v.w < 0.0f) ? 8u : 0u);
        d[gi] = (uint16_t)(n0 | (n1 << 4) | (n2 << 8) | (n3 << 12));
    }
}

// ---------------- MX-FP4 MFMA GEMM, 256x256, 4-phase, single-barrier --------
// R10 schedule with the pre-MFMA barrier removed. Ledger (verified single-
// barrier safety): a stage to buffer X only occurs in a phase after X's old
// readers' MFMA (whose lgkm-wait drains those reads) and the end-barrier the
// readers passed. Phase = [reads; stage; MFMA; (vmcnt); barrier]. Waves on a
// SIMD now decouple within the phase: one wave's ds_reads overlap the other's
// MFMA cluster; compiler interleaves via counted lgkmcnt.
__global__ __launch_bounds__(512, 2) void bgemm_fp4(
        const char*  __restrict__ Xp,   // [NTOK][KB4] fp4-packed signs
        const char*  __restrict__ Wp,   // [OUTF][KB4]
        const float* __restrict__ bias, // [OUTF]
        float*       __restrict__ out)  // [NTOK][OUTF]
{
    __shared__ __align__(16) char As[2][32768];
    __shared__ __align__(16) char Bs[2][32768];

    const int tid  = threadIdx.x;
    const int lane = tid & 63;
    const int wid  = tid >> 6;
    const int wr   = wid >> 2;          // 0..1 (128-row half)
    const int wc   = wid & 3;           // 0..3 (64-col quarter)
    const int cl   = lane & 15;
    const int rg   = lane >> 4;

    int row0, col0;
    full_swizzle(blockIdx.x, row0, col0);

    const int rr     = tid >> 3;                       // 0..63
    const int colOff = ((tid & 7) << 4) ^ ((rr & 7) << 4);
    const char* gA = Xp + (size_t)(row0 + rr) * KB4 + colOff;
    const char* gB = Wp + (size_t)(col0 + rr) * KB4 + colOff;
    const int d0 = tid * 16;

#define STGF(arr, p, g, ktB) do { \
    GLOAD16((g) + (size_t)0   * KB4 + (ktB), &arr[p][d0]); \
    GLOAD16((g) + (size_t)64  * KB4 + (ktB), &arr[p][8192 + d0]); \
    GLOAD16((g) + (size_t)128 * KB4 + (ktB), &arr[p][16384 + d0]); \
    GLOAD16((g) + (size_t)192 * KB4 + (ktB), &arr[p][24576 + d0]); \
} while (0)

    const int aRow = (wr * 128 + cl) * 128;
    const int bRow = (wc * 64 + cl) * 128;
    const int kq0  = (rg << 4) ^ ((cl & 7) << 4);
    const int kq1  = kq0 ^ 64;

    f32x4 acc[8][4];
#pragma unroll
    for (int m = 0; m < 8; ++m)
#pragma unroll
        for (int n = 0; n < 4; ++n)
#pragma unroll
            for (int j = 0; j < 4; ++j) acc[m][n][j] = 0.0f;

    i32x4 af[4][2], bf[4][2];

#define LDA(p, MH) do { \
    _Pragma("unroll") for (int m = 0; m < 4; ++m) { \
        af[m][0] = *reinterpret_cast<const i32x4*>(&As[p][aRow + ((MH) * 4 + m) * 2048 + kq0]); \
        af[m][1] = *reinterpret_cast<const i32x4*>(&As[p][aRow + ((MH) * 4 + m) * 2048 + kq1]); \
    } } while (0)
#define LDBALL(p) do { \
    _Pragma("unroll") for (int n = 0; n < 4; ++n) { \
        bf[n][0] = *reinterpret_cast<const i32x4*>(&Bs[p][bRow + (n) * 2048 + kq0]); \
        bf[n][1] = *reinterpret_cast<const i32x4*>(&Bs[p][bRow + (n) * 2048 + kq1]); \
    } } while (0)
// kk outer so consecutive MFMAs hit different acc registers.
#define MMALL(MH) do { \
    __builtin_amdgcn_s_setprio(1); \
    _Pragma("unroll") for (int kk = 0; kk < 2; ++kk) \
    _Pragma("unroll") for (int m = 0; m < 4; ++m) \
    _Pragma("unroll") for (int n = 0; n < 4; ++n) { \
        i32x8 a8 = {af[m][kk][0], af[m][kk][1], af[m][kk][2], af[m][kk][3], 0, 0, 0, 0}; \
        i32x8 b8 = {bf[n][kk][0], bf[n][kk][1], bf[n][kk][2], bf[n][kk][3], 0, 0, 0, 0}; \
        acc[(MH) * 4 + m][n] = __builtin_amdgcn_mfma_scale_f32_16x16x128_f8f6f4( \
            a8, b8, acc[(MH) * 4 + m][n], 4, 4, 0, 0x7F7F7F7F, 0, 0x7F7F7F7F); \
    } \
    __builtin_amdgcn_s_setprio(0); \
} while (0)

    // ---- prologue: tile0 (A,B) + tile1 B = 12 gloads; retire tile0 --------
    STGF(As, 0, gA, 0);
    STGF(Bs, 0, gB, 0);
    STGF(Bs, 1, gB, 128);
    VMCNT4();
    SBARE();

    // ---- main loop: tile 2i (p0) ph0-1, tile 2i+1 (p1) ph2-3 --------------
    int kb = 0;  // = i*256 bytes
#pragma unroll 1
    for (int i = 0; i < 7; ++i, kb += 256) {
        // ph0: reads A(p0,MH0)+B(p0) ; stage A.p1(t+1) ; MFMA(MH0)
        LDA(0, 0); LDBALL(0);
        STGF(As, 1, gA, kb + 128);
        MMALL(0);
        SBARE();
        // ph1: reads A(p0,MH1) ; stage B.p0(t+2) ; MFMA(MH1) ; vmcnt(4)
        LDA(0, 1);
        STGF(Bs, 0, gB, kb + 256);
        MMALL(1);
        VMCNT4(); SBARE();
        // ph2: reads A(p1,MH0)+B(p1) ; stage A.p0(t+2) ; MFMA(MH0)
        LDA(1, 0); LDBALL(1);
        STGF(As, 0, gA, kb + 256);
        MMALL(0);
        SBARE();
        // ph3: reads A(p1,MH1) ; stage B.p1(t+3) ; MFMA(MH1) ; vmcnt(4)
        LDA(1, 1);
        STGF(Bs, 1, gB, kb + 384);
        MMALL(1);
        VMCNT4(); SBARE();
    }

    // ---- epilogue: stage A.p1 (tile15 @1920); drain; compute t14, t15 -----
    STGF(As, 1, gA, 1920);
    VMCNT0();
    SBARE();
    LDA(0, 0); LDBALL(0); MMALL(0);
    LDA(0, 1);            MMALL(1);
    LDA(1, 0); LDBALL(1); MMALL(0);
    LDA(1, 1);            MMALL(1);

    // ---- C write: C/D layout col=lane&15, row=rg*4+j (shape-determined) ---
    float bv[4];
#pragma unroll
    for (int n = 0; n < 4; ++n) bv[n] = bias[col0 + wc * 64 + n * 16 + cl];

#pragma unroll
    for (int m = 0; m < 8; ++m) {
        int rowbase = row0 + wr * 128 + m * 16 + rg * 4;
#pragma unroll
        for (int j = 0; j < 4; ++j) {
            size_t rb = (size_t)(rowbase + j) * OUTF;
#pragma unroll
            for (int n = 0; n < 4; ++n) {
                int col = col0 + wc * 64 + n * 16 + cl;
                out[rb + col] = acc[m][n][j] + bv[n];
            }
        }
    }
#undef STGF
#undef LDA
#undef LDBALL
#undef MMALL
}

// ================= i8 path (R7 core, verified) — ws fallback ================
__global__ void pack_i8(const float* __restrict__ x, const float* __restrict__ w,
                        char* __restrict__ xp, char* __restrict__ wp,
                        int gx, int gtot) {
    int gtid = blockIdx.x * blockDim.x + threadIdx.x;
    int nthr = gridDim.x * blockDim.x;
    for (int g = gtid; g < gtot; g += nthr) {
        const float* src;
        char* dst;
        int gi;
        if (g < gx) { src = x; dst = xp; gi = g; }
        else        { src = w; dst = wp; gi = g - gx; }
        const float4* s4 = reinterpret_cast<const float4*>(src + (size_t)gi * 16);
        int words[4];
#pragma unroll
        for (int q = 0; q < 4; ++q) {
            float4 v = s4[q];
            int b0 = (v.x < 0.0f) ? 0xFF : 0x01;
            int b1 = (v.y < 0.0f) ? 0xFF : 0x01;
            int b2 = (v.z < 0.0f) ? 0xFF : 0x01;
            int b3 = (v.w < 0.0f) ? 0xFF : 0x01;
            words[q] = b0 | (b1 << 8) | (b2 << 16) | (b3 << 24);
        }
        int4 o = make_int4(words[0], words[1], words[2], words[3]);
        *reinterpret_cast<int4*>(dst + (size_t)gi * 16) = o;
    }
}

__global__ __launch_bounds__(512, 2) void bgemm_i8_4ph(
        const char*  __restrict__ Xp, const char* __restrict__ Wp,
        const float* __restrict__ bias, float* __restrict__ out)
{
    __shared__ __align__(16) char As[2][32768];
    __shared__ __align__(16) char Bs[2][32768];

    const int tid  = threadIdx.x;
    const int lane = tid & 63;
    const int wid  = tid >> 6;
    const int wr   = wid >> 2;
    const int wc   = wid & 3;
    const int cl   = lane & 15;
    const int rg   = lane >> 4;

    int row0, col0;
    full_swizzle(blockIdx.x, row0, col0);

    const int rr     = tid >> 3;
    const int colOff = ((tid & 7) << 4) ^ ((rr & 7) << 4);
    const char* gA = Xp + (size_t)(row0 + rr) * KDIM + colOff;
    const char* gB = Wp + (size_t)(col0 + rr) * KDIM + colOff;
    const int d0 = tid * 16;

#define STGF(arr, p, g, ktB) do { \
    GLOAD16((g) + (size_t)0   * KDIM + (ktB), &arr[p][d0]); \
    GLOAD16((g) + (size_t)64  * KDIM + (ktB), &arr[p][8192 + d0]); \
    GLOAD16((g) + (size_t)128 * KDIM + (ktB), &arr[p][16384 + d0]); \
    GLOAD16((g) + (size_t)192 * KDIM + (ktB), &arr[p][24576 + d0]); \
} while (0)

    const int aRow = (wr * 128 + cl) * 128;
    const int bRow = (wc * 64 + cl) * 128;
    const int kq0  = (rg << 4) ^ ((cl & 7) << 4);
    const int kq1  = kq0 ^ 64;

    i32x4 acc[8][4];
#pragma unroll
    for (int m = 0; m < 8; ++m)
#pragma unroll
        for (int n = 0; n < 4; ++n)
#pragma unroll
            for (int j = 0; j < 4; ++j) acc[m][n][j] = 0;

    i32x4 af[4][2], bf[4][2];

#define LDA(p, MH) do { \
    _Pragma("unroll") for (int m = 0; m < 4; ++m) { \
        af[m][0] = *reinterpret_cast<const i32x4*>(&As[p][aRow + ((MH) * 4 + m) * 2048 + kq0]); \
        af[m][1] = *reinterpret_cast<const i32x4*>(&As[p][aRow + ((MH) * 4 + m) * 2048 + kq1]); \
    } } while (0)
#define LDBALL(p) do { \
    _Pragma("unroll") for (int n = 0; n < 4; ++n) { \
        bf[n][0] = *reinterpret_cast<const i32x4*>(&Bs[p][bRow + (n) * 2048 + kq0]); \
        bf[n][1] = *reinterpret_cast<const i32x4*>(&Bs[p][bRow + (n) * 2048 + kq1]); \
    } } while (0)
#define MMALL(MH) do { \
    __builtin_amdgcn_s_setprio(1); \
    _Pragma("unroll") for (int m = 0; m < 4; ++m) \
    _Pragma("unroll") for (int n = 0; n < 4; ++n) \
    _Pragma("unroll") for (int kk = 0; kk < 2; ++kk) \
        acc[(MH) * 4 + m][n] = __builtin_amdgcn_mfma_i32_16x16x64_i8( \
            af[m][kk], bf[n][kk], acc[(MH) * 4 + m][n], 0, 0, 0); \
    __builtin_amdgcn_s_setprio(0); \
} while (0)

    STGF(As, 0, gA, 0);
    STGF(Bs, 0, gB, 0);
    STGF(Bs, 1, gB, 128);
    VMCNT4();
    SBARE();

    int kb = 0;
#pragma unroll 1
    for (int i = 0; i < 15; ++i, kb += 256) {
        LDA(0, 0); LDBALL(0);
        STGF(As, 1, gA, kb + 128);
        MMALL(0);
        SBARE();
        LDA(0, 1);
        STGF(Bs, 0, gB, kb + 256);
        MMALL(1);
        VMCNT4(); SBARE();
        LDA(1, 0); LDBALL(1);
        STGF(As, 0, gA, kb + 256);
        MMALL(0);
        SBARE();
        LDA(1, 1);
        STGF(Bs, 1, gB, kb + 384);
        MMALL(1);
        VMCNT4(); SBARE();
    }

    STGF(As, 1, gA, 3968);
    VMCNT0();
    SBARE();
    LDA(0, 0); LDBALL(0); MMALL(0);
    LDA(0, 1);            MMALL(1);
    LDA(1, 0); LDBALL(1); MMALL(0);
    LDA(1, 1);            MMALL(1);

    float bv[4];
#pragma unroll
    for (int n = 0; n < 4; ++n) bv[n] = bias[col0 + wc * 64 + n * 16 + cl];

#pragma unroll
    for (int m = 0; m < 8; ++m) {
        int rowbase = row0 + wr * 128 + m * 16 + rg * 4;
#pragma unroll
        for (int j = 0; j < 4; ++j) {
            size_t rb = (size_t)(rowbase + j) * OUTF;
#pragma unroll
            for (int n = 0; n < 4; ++n) {
                int col = col0 + wc * 64 + n * 16 + cl;
                out[rb + col] = (float)acc[m][n][j] + bv[n];
            }
        }
    }
#undef STGF
#undef LDA
#undef LDBALL
#undef MMALL
}

// ================= popcount fallback (round-1, known-good) ==================
#define KW   64
#define LSTRIDE 66

__global__ void pack_both_fb(const float* __restrict__ x, const float* __restrict__ w,
                             uint64_t* __restrict__ xp, uint64_t* __restrict__ wp,
                             int nx, int ntot) {
    int gtid  = blockIdx.x * blockDim.x + threadIdx.x;
    int lane  = threadIdx.x & 63;
    int wave  = gtid >> 6;
    int nwaves = (gridDim.x * blockDim.x) >> 6;
    for (int q = wave; q < ntot; q += nwaves) {
        const float* src; uint64_t* dst; int qi;
        if (q < nx) { src = x; dst = xp; qi = q; }
        else        { src = w; dst = wp; qi = q - nx; }
        float v = src[(size_t)qi * 64 + lane];
        unsigned long long m = __ballot(v < 0.0f);
        if (lane == 0) dst[qi] = (uint64_t)m;
    }
}

__global__ __launch_bounds__(512, 2) void bgemm_popc_fb(
        const uint64_t* __restrict__ xp, const uint64_t* __restrict__ wp,
        const float* __restrict__ bias, float* __restrict__ out)
{
    __shared__ uint64_t xs[128 * LSTRIDE];
    __shared__ uint64_t ws[128 * LSTRIDE];
    const int tid  = threadIdx.x;
    const int row0 = blockIdx.y * 128;
    const int col0 = blockIdx.x * 128;
    {
        const uint64_t* xg = xp + (size_t)row0 * KW;
        const uint64_t* wg = wp + (size_t)col0 * KW;
#pragma unroll
        for (int m = 0; m < 8; ++m) {
            int q = (m * 512 + tid) * 2;
            int r = q >> 6;
            int k = q & 63;
            ulonglong2 vx = *reinterpret_cast<const ulonglong2*>(xg + q);
            xs[r * LSTRIDE + k] = vx.x; xs[r * LSTRIDE + k + 1] = vx.y;
            ulonglong2 vw = *reinterpret_cast<const ulonglong2*>(wg + q);
            ws[r * LSTRIDE + k] = vw.x; ws[r * LSTRIDE + k + 1] = vw.y;
        }
    }
    __syncthreads();
    const int tx = tid & 15;
    const int ty = tid >> 4;
    int acc[4][8];
#pragma unroll
    for (int i = 0; i < 4; ++i)
#pragma unroll
        for (int j = 0; j < 8; ++j) acc[i][j] = 0;
    const uint64_t* xrow = xs + ty * 4 * LSTRIDE;
    const uint64_t* wrow = ws + tx * LSTRIDE;
#pragma unroll 4
    for (int kk = 0; kk < KW; kk += 2) {
        ulonglong2 a[4]; ulonglong2 b[8];
#pragma unroll
        for (int i = 0; i < 4; ++i)
            a[i] = *reinterpret_cast<const ulonglong2*>(xrow + i * LSTRIDE + kk);
#pragma unroll
        for (int j = 0; j < 8; ++j)
            b[j] = *reinterpret_cast<const ulonglong2*>(wrow + j * 16 * LSTRIDE + kk);
#pragma unroll
        for (int i = 0; i < 4; ++i)
#pragma unroll
            for (int j = 0; j < 8; ++j)
                acc[i][j] += __builtin_popcountll(a[i].x ^ b[j].x)
                           + __builtin_popcountll(a[i].y ^ b[j].y);
    }
    float bcol[8];
#pragma unroll
    for (int j = 0; j < 8; ++j) bcol[j] = bias[col0 + tx + 16 * j];
#pragma unroll
    for (int i = 0; i < 4; ++i) {
        size_t r = (size_t)(row0 + ty * 4 + i);
#pragma unroll
        for (int j = 0; j < 8; ++j) {
            int c = col0 + tx + 16 * j;
            out[r * OUTF + c] = (float)(INF - 2 * acc[i][j]) + bcol[j];
        }
    }
}
// ============================================================================

extern "C" void kernel_launch(void* const* d_in, const int* in_sizes, int n_in,
                              void* d_out, int out_size, void* d_ws, size_t ws_size,
                              hipStream_t stream) {
    const float* x    = (const float*)d_in[0];
    const float* w    = (const float*)d_in[1];
    const float* bias = (const float*)d_in[2];
    float* out = (float*)d_out;

    const size_t need4 = (size_t)NTOK * KB4 + (size_t)OUTF * KB4;   // 25.2 MB
    const size_t need8 = (size_t)NTOK * KDIM + (size_t)OUTF * KDIM; // 50.3 MB

    if (ws_size >= need4) {
        char* xp = (char*)d_ws;
        char* wp = xp + (size_t)NTOK * KB4;
        const int gx4   = NTOK * KDIM / 4;                // 8388608 float4 groups
        const int gtot4 = gx4 + OUTF * KDIM / 4;          // 12582912
        pack_fp4<<<2048, 256, 0, stream>>>(x, w, xp, wp, gx4, gtot4);
        bgemm_fp4<<<512, 512, 0, stream>>>(xp, wp, bias, out);
    } else if (ws_size >= need8) {
        char* xp = (char*)d_ws;
        char* wp = xp + (size_t)NTOK * KDIM;
        const int gx   = NTOK * KDIM / 16;
        const int gtot = gx + OUTF * KDIM / 16;
        pack_i8<<<2048, 256, 0, stream>>>(x, w, xp, wp, gx, gtot);
        bgemm_i8_4ph<<<512, 512, 0, stream>>>(xp, wp, bias, out);
    } else {
        uint64_t* xp = (uint64_t*)d_ws;
        uint64_t* wp = xp + (size_t)NTOK * KW;
        const int nx   = NTOK * KW;
        const int ntot = nx + OUTF * KW;
        pack_both_fb<<<2048, 256, 0, stream>>>(x, w, xp, wp, nx, ntot);
        dim3 grid(OUTF / 128, NTOK / 128);
        bgemm_popc_fb<<<grid, 512, 0, stream>>>(xp, wp, bias, out);
    }
}

// Round 13
// 126.230 us; speedup vs baseline: 1.4874x; 1.0379x over previous
//
#include <hip/hip_runtime.h>
#include <stdint.h>

#define NTOK 8192
#define INF  4096
#define OUTF 4096
#define KDIM 4096
#define KB4  2048   // packed fp4 row bytes (2 elems/byte)

using i32x4 = __attribute__((ext_vector_type(4))) int;
using i32x8 = __attribute__((ext_vector_type(8))) int;
using f32x4 = __attribute__((ext_vector_type(4))) float;

#define GLOAD16(gp, lp) __builtin_amdgcn_global_load_lds( \
    (const __attribute__((address_space(1))) uint32_t*)(gp), \
    (__attribute__((address_space(3))) uint32_t*)(lp), 16, 0, 0)

#define SBARE()  do { __builtin_amdgcn_s_barrier(); __builtin_amdgcn_sched_barrier(0); } while (0)
#define VMCNT4() do { asm volatile("s_waitcnt vmcnt(4)" ::: "memory"); __builtin_amdgcn_sched_barrier(0); } while (0)
#define VMCNT0() do { asm volatile("s_waitcnt vmcnt(0)" ::: "memory"); __builtin_amdgcn_sched_barrier(0); } while (0)

// full-grid XCD swizzle (512 blocks, 8 XCDs)
__device__ __forceinline__ void full_swizzle(int orig, int& row0, int& col0) {
    const int wgid  = ((orig & 7) << 6) | (orig >> 3);
    const int chunk = wgid >> 6;
    const int c     = wgid & 63;
    row0 = ((chunk << 2) | (c & 3)) * 256;
    col0 = (c >> 2) * 256;
}

// ---------------- pack pass v4: 16 floats/thread, 4 loads in flight ---------
// Each thread: 4 independent float4 loads (64 B contiguous) -> 1 uint64 store.
// MLP=4 attacks the observed ~1-request-per-wave latency bound.
__device__ __forceinline__ unsigned int nib16(float4 v) {
    return (0x2u | ((v.x < 0.0f) ? 8u : 0u))
         | ((0x2u | ((v.y < 0.0f) ? 8u : 0u)) << 4)
         | ((0x2u | ((v.z < 0.0f) ? 8u : 0u)) << 8)
         | ((0x2u | ((v.w < 0.0f) ? 8u : 0u)) << 12);
}

__global__ void pack_fp4(const float* __restrict__ x, const float* __restrict__ w,
                         char* __restrict__ xp, char* __restrict__ wp,
                         int gx, int gtot) {
    int gtid = blockIdx.x * blockDim.x + threadIdx.x;
    int nthr = gridDim.x * blockDim.x;
    for (int g = gtid; g < gtot; g += nthr) {
        const float4* s;
        uint64_t* d;
        int gi;
        if (g < gx) { s = (const float4*)x; d = (uint64_t*)xp; gi = g; }
        else        { s = (const float4*)w; d = (uint64_t*)wp; gi = g - gx; }
        const float4* sp = s + (size_t)gi * 4;
        float4 v0 = sp[0];
        float4 v1 = sp[1];
        float4 v2 = sp[2];
        float4 v3 = sp[3];
        uint32_t lo = nib16(v0) | (nib16(v1) << 16);
        uint32_t hi = nib16(v2) | (nib16(v3) << 16);
        d[gi] = (uint64_t)lo | ((uint64_t)hi << 32);
    }
}

// ---------------- MX-FP4 MFMA GEMM, 256x256, 4-phase (R11-proven core) ------
// EXACT revert to the R11 kernel (absmax 0, ~80us cold / ~50us warm):
// B-fragments read ONCE per tile (before any same-parity stage) and persisted
// across both phases — this is what makes the single-barrier ledger race-free.
// R12's per-substep B re-read raced with the B-stage; do not reintroduce.
__global__ __launch_bounds__(512, 2) void bgemm_fp4(
        const char*  __restrict__ Xp,   // [NTOK][KB4] fp4-packed signs
        const char*  __restrict__ Wp,   // [OUTF][KB4]
        const float* __restrict__ bias, // [OUTF]
        float*       __restrict__ out)  // [NTOK][OUTF]
{
    __shared__ __align__(16) char As[2][32768];
    __shared__ __align__(16) char Bs[2][32768];

    const int tid  = threadIdx.x;
    const int lane = tid & 63;
    const int wid  = tid >> 6;
    const int wr   = wid >> 2;          // 0..1 (128-row half)
    const int wc   = wid & 3;           // 0..3 (64-col quarter)
    const int cl   = lane & 15;
    const int rg   = lane >> 4;

    int row0, col0;
    full_swizzle(blockIdx.x, row0, col0);

    const int rr     = tid >> 3;                       // 0..63
    const int colOff = ((tid & 7) << 4) ^ ((rr & 7) << 4);
    const char* gA = Xp + (size_t)(row0 + rr) * KB4 + colOff;
    const char* gB = Wp + (size_t)(col0 + rr) * KB4 + colOff;
    const int d0 = tid * 16;

#define STGF(arr, p, g, ktB) do { \
    GLOAD16((g) + (size_t)0   * KB4 + (ktB), &arr[p][d0]); \
    GLOAD16((g) + (size_t)64  * KB4 + (ktB), &arr[p][8192 + d0]); \
    GLOAD16((g) + (size_t)128 * KB4 + (ktB), &arr[p][16384 + d0]); \
    GLOAD16((g) + (size_t)192 * KB4 + (ktB), &arr[p][24576 + d0]); \
} while (0)

    const int aRow = (wr * 128 + cl) * 128;
    const int bRow = (wc * 64 + cl) * 128;
    const int kq0  = (rg << 4) ^ ((cl & 7) << 4);
    const int kq1  = kq0 ^ 64;

    f32x4 acc[8][4];
#pragma unroll
    for (int m = 0; m < 8; ++m)
#pragma unroll
        for (int n = 0; n < 4; ++n)
#pragma unroll
            for (int j = 0; j < 4; ++j) acc[m][n][j] = 0.0f;

    i32x4 af[4][2], bf[4][2];

#define LDA(p, MH) do { \
    _Pragma("unroll") for (int m = 0; m < 4; ++m) { \
        af[m][0] = *reinterpret_cast<const i32x4*>(&As[p][aRow + ((MH) * 4 + m) * 2048 + kq0]); \
        af[m][1] = *reinterpret_cast<const i32x4*>(&As[p][aRow + ((MH) * 4 + m) * 2048 + kq1]); \
    } } while (0)
#define LDBALL(p) do { \
    _Pragma("unroll") for (int n = 0; n < 4; ++n) { \
        bf[n][0] = *reinterpret_cast<const i32x4*>(&Bs[p][bRow + (n) * 2048 + kq0]); \
        bf[n][1] = *reinterpret_cast<const i32x4*>(&Bs[p][bRow + (n) * 2048 + kq1]); \
    } } while (0)
// kk outer so consecutive MFMAs hit different acc registers.
#define MMALL(MH) do { \
    __builtin_amdgcn_s_setprio(1); \
    _Pragma("unroll") for (int kk = 0; kk < 2; ++kk) \
    _Pragma("unroll") for (int m = 0; m < 4; ++m) \
    _Pragma("unroll") for (int n = 0; n < 4; ++n) { \
        i32x8 a8 = {af[m][kk][0], af[m][kk][1], af[m][kk][2], af[m][kk][3], 0, 0, 0, 0}; \
        i32x8 b8 = {bf[n][kk][0], bf[n][kk][1], bf[n][kk][2], bf[n][kk][3], 0, 0, 0, 0}; \
        acc[(MH) * 4 + m][n] = __builtin_amdgcn_mfma_scale_f32_16x16x128_f8f6f4( \
            a8, b8, acc[(MH) * 4 + m][n], 4, 4, 0, 0x7F7F7F7F, 0, 0x7F7F7F7F); \
    } \
    __builtin_amdgcn_s_setprio(0); \
} while (0)

    // ---- prologue: tile0 (A,B) + tile1 B = 12 gloads; retire tile0 --------
    STGF(As, 0, gA, 0);
    STGF(Bs, 0, gB, 0);
    STGF(Bs, 1, gB, 128);
    VMCNT4();
    SBARE();

    // ---- main loop: tile 2i (p0) ph0-1, tile 2i+1 (p1) ph2-3 --------------
    int kb = 0;  // = i*256 bytes
#pragma unroll 1
    for (int i = 0; i < 7; ++i, kb += 256) {
        // ph0: reads A(p0,MH0)+B(p0) ; stage A.p1(t+1) ; MFMA(MH0)
        LDA(0, 0); LDBALL(0);
        STGF(As, 1, gA, kb + 128);
        MMALL(0);
        SBARE();
        // ph1: reads A(p0,MH1) ; stage B.p0(t+2) ; MFMA(MH1) ; vmcnt(4)
        LDA(0, 1);
        STGF(Bs, 0, gB, kb + 256);
        MMALL(1);
        VMCNT4(); SBARE();
        // ph2: reads A(p1,MH0)+B(p1) ; stage A.p0(t+2) ; MFMA(MH0)
        LDA(1, 0); LDBALL(1);
        STGF(As, 0, gA, kb + 256);
        MMALL(0);
        SBARE();
        // ph3: reads A(p1,MH1) ; stage B.p1(t+3) ; MFMA(MH1) ; vmcnt(4)
        LDA(1, 1);
        STGF(Bs, 1, gB, kb + 384);
        MMALL(1);
        VMCNT4(); SBARE();
    }

    // ---- epilogue: stage A.p1 (tile15 @1920); drain; compute t14, t15 -----
    STGF(As, 1, gA, 1920);
    VMCNT0();
    SBARE();
    LDA(0, 0); LDBALL(0); MMALL(0);
    LDA(0, 1);            MMALL(1);
    LDA(1, 0); LDBALL(1); MMALL(0);
    LDA(1, 1);            MMALL(1);

    // ---- C write: C/D layout col=lane&15, row=rg*4+j (shape-determined) ---
    float bv[4];
#pragma unroll
    for (int n = 0; n < 4; ++n) bv[n] = bias[col0 + wc * 64 + n * 16 + cl];

#pragma unroll
    for (int m = 0; m < 8; ++m) {
        int rowbase = row0 + wr * 128 + m * 16 + rg * 4;
#pragma unroll
        for (int j = 0; j < 4; ++j) {
            size_t rb = (size_t)(rowbase + j) * OUTF;
#pragma unroll
            for (int n = 0; n < 4; ++n) {
                int col = col0 + wc * 64 + n * 16 + cl;
                out[rb + col] = acc[m][n][j] + bv[n];
            }
        }
    }
#undef STGF
#undef LDA
#undef LDBALL
#undef MMALL
}

// ================= i8 path (R7 core, verified) — ws fallback ================
__global__ void pack_i8(const float* __restrict__ x, const float* __restrict__ w,
                        char* __restrict__ xp, char* __restrict__ wp,
                        int gx, int gtot) {
    int gtid = blockIdx.x * blockDim.x + threadIdx.x;
    int nthr = gridDim.x * blockDim.x;
    for (int g = gtid; g < gtot; g += nthr) {
        const float* src;
        char* dst;
        int gi;
        if (g < gx) { src = x; dst = xp; gi = g; }
        else        { src = w; dst = wp; gi = g - gx; }
        const float4* s4 = reinterpret_cast<const float4*>(src + (size_t)gi * 16);
        int words[4];
#pragma unroll
        for (int q = 0; q < 4; ++q) {
            float4 v = s4[q];
            int b0 = (v.x < 0.0f) ? 0xFF : 0x01;
            int b1 = (v.y < 0.0f) ? 0xFF : 0x01;
            int b2 = (v.z < 0.0f) ? 0xFF : 0x01;
            int b3 = (v.w < 0.0f) ? 0xFF : 0x01;
            words[q] = b0 | (b1 << 8) | (b2 << 16) | (b3 << 24);
        }
        int4 o = make_int4(words[0], words[1], words[2], words[3]);
        *reinterpret_cast<int4*>(dst + (size_t)gi * 16) = o;
    }
}

__global__ __launch_bounds__(512, 2) void bgemm_i8_4ph(
        const char*  __restrict__ Xp, const char* __restrict__ Wp,
        const float* __restrict__ bias, float* __restrict__ out)
{
    __shared__ __align__(16) char As[2][32768];
    __shared__ __align__(16) char Bs[2][32768];

    const int tid  = threadIdx.x;
    const int lane = tid & 63;
    const int wid  = tid >> 6;
    const int wr   = wid >> 2;
    const int wc   = wid & 3;
    const int cl   = lane & 15;
    const int rg   = lane >> 4;

    int row0, col0;
    full_swizzle(blockIdx.x, row0, col0);

    const int rr     = tid >> 3;
    const int colOff = ((tid & 7) << 4) ^ ((rr & 7) << 4);
    const char* gA = Xp + (size_t)(row0 + rr) * KDIM + colOff;
    const char* gB = Wp + (size_t)(col0 + rr) * KDIM + colOff;
    const int d0 = tid * 16;

#define STGF(arr, p, g, ktB) do { \
    GLOAD16((g) + (size_t)0   * KDIM + (ktB), &arr[p][d0]); \
    GLOAD16((g) + (size_t)64  * KDIM + (ktB), &arr[p][8192 + d0]); \
    GLOAD16((g) + (size_t)128 * KDIM + (ktB), &arr[p][16384 + d0]); \
    GLOAD16((g) + (size_t)192 * KDIM + (ktB), &arr[p][24576 + d0]); \
} while (0)

    const int aRow = (wr * 128 + cl) * 128;
    const int bRow = (wc * 64 + cl) * 128;
    const int kq0  = (rg << 4) ^ ((cl & 7) << 4);
    const int kq1  = kq0 ^ 64;

    i32x4 acc[8][4];
#pragma unroll
    for (int m = 0; m < 8; ++m)
#pragma unroll
        for (int n = 0; n < 4; ++n)
#pragma unroll
            for (int j = 0; j < 4; ++j) acc[m][n][j] = 0;

    i32x4 af[4][2], bf[4][2];

#define LDA(p, MH) do { \
    _Pragma("unroll") for (int m = 0; m < 4; ++m) { \
        af[m][0] = *reinterpret_cast<const i32x4*>(&As[p][aRow + ((MH) * 4 + m) * 2048 + kq0]); \
        af[m][1] = *reinterpret_cast<const i32x4*>(&As[p][aRow + ((MH) * 4 + m) * 2048 + kq1]); \
    } } while (0)
#define LDBALL(p) do { \
    _Pragma("unroll") for (int n = 0; n < 4; ++n) { \
        bf[n][0] = *reinterpret_cast<const i32x4*>(&Bs[p][bRow + (n) * 2048 + kq0]); \
        bf[n][1] = *reinterpret_cast<const i32x4*>(&Bs[p][bRow + (n) * 2048 + kq1]); \
    } } while (0)
#define MMALL(MH) do { \
    __builtin_amdgcn_s_setprio(1); \
    _Pragma("unroll") for (int m = 0; m < 4; ++m) \
    _Pragma("unroll") for (int n = 0; n < 4; ++n) \
    _Pragma("unroll") for (int kk = 0; kk < 2; ++kk) \
        acc[(MH) * 4 + m][n] = __builtin_amdgcn_mfma_i32_16x16x64_i8( \
            af[m][kk], bf[n][kk], acc[(MH) * 4 + m][n], 0, 0, 0); \
    __builtin_amdgcn_s_setprio(0); \
} while (0)

    STGF(As, 0, gA, 0);
    STGF(Bs, 0, gB, 0);
    STGF(Bs, 1, gB, 128);
    VMCNT4();
    SBARE();

    int kb = 0;
#pragma unroll 1
    for (int i = 0; i < 15; ++i, kb += 256) {
        LDA(0, 0); LDBALL(0);
        STGF(As, 1, gA, kb + 128);
        MMALL(0);
        SBARE();
        LDA(0, 1);
        STGF(Bs, 0, gB, kb + 256);
        MMALL(1);
        VMCNT4(); SBARE();
        LDA(1, 0); LDBALL(1);
        STGF(As, 0, gA, kb + 256);
        MMALL(0);
        SBARE();
        LDA(1, 1);
        STGF(Bs, 1, gB, kb + 384);
        MMALL(1);
        VMCNT4(); SBARE();
    }

    STGF(As, 1, gA, 3968);
    VMCNT0();
    SBARE();
    LDA(0, 0); LDBALL(0); MMALL(0);
    LDA(0, 1);            MMALL(1);
    LDA(1, 0); LDBALL(1); MMALL(0);
    LDA(1, 1);            MMALL(1);

    float bv[4];
#pragma unroll
    for (int n = 0; n < 4; ++n) bv[n] = bias[col0 + wc * 64 + n * 16 + cl];

#pragma unroll
    for (int m = 0; m < 8; ++m) {
        int rowbase = row0 + wr * 128 + m * 16 + rg * 4;
#pragma unroll
        for (int j = 0; j < 4; ++j) {
            size_t rb = (size_t)(rowbase + j) * OUTF;
#pragma unroll
            for (int n = 0; n < 4; ++n) {
                int col = col0 + wc * 64 + n * 16 + cl;
                out[rb + col] = (float)acc[m][n][j] + bv[n];
            }
        }
    }
#undef STGF
#undef LDA
#undef LDBALL
#undef MMALL
}

// ================= popcount fallback (round-1, known-good) ==================
#define KW   64
#define LSTRIDE 66

__global__ void pack_both_fb(const float* __restrict__ x, const float* __restrict__ w,
                             uint64_t* __restrict__ xp, uint64_t* __restrict__ wp,
                             int nx, int ntot) {
    int gtid  = blockIdx.x * blockDim.x + threadIdx.x;
    int lane  = threadIdx.x & 63;
    int wave  = gtid >> 6;
    int nwaves = (gridDim.x * blockDim.x) >> 6;
    for (int q = wave; q < ntot; q += nwaves) {
        const float* src; uint64_t* dst; int qi;
        if (q < nx) { src = x; dst = xp; qi = q; }
        else        { src = w; dst = wp; qi = q - nx; }
        float v = src[(size_t)qi * 64 + lane];
        unsigned long long m = __ballot(v < 0.0f);
        if (lane == 0) dst[qi] = (uint64_t)m;
    }
}

__global__ __launch_bounds__(512, 2) void bgemm_popc_fb(
        const uint64_t* __restrict__ xp, const uint64_t* __restrict__ wp,
        const float* __restrict__ bias, float* __restrict__ out)
{
    __shared__ uint64_t xs[128 * LSTRIDE];
    __shared__ uint64_t ws[128 * LSTRIDE];
    const int tid  = threadIdx.x;
    const int row0 = blockIdx.y * 128;
    const int col0 = blockIdx.x * 128;
    {
        const uint64_t* xg = xp + (size_t)row0 * KW;
        const uint64_t* wg = wp + (size_t)col0 * KW;
#pragma unroll
        for (int m = 0; m < 8; ++m) {
            int q = (m * 512 + tid) * 2;
            int r = q >> 6;
            int k = q & 63;
            ulonglong2 vx = *reinterpret_cast<const ulonglong2*>(xg + q);
            xs[r * LSTRIDE + k] = vx.x; xs[r * LSTRIDE + k + 1] = vx.y;
            ulonglong2 vw = *reinterpret_cast<const ulonglong2*>(wg + q);
            ws[r * LSTRIDE + k] = vw.x; ws[r * LSTRIDE + k + 1] = vw.y;
        }
    }
    __syncthreads();
    const int tx = tid & 15;
    const int ty = tid >> 4;
    int acc[4][8];
#pragma unroll
    for (int i = 0; i < 4; ++i)
#pragma unroll
        for (int j = 0; j < 8; ++j) acc[i][j] = 0;
    const uint64_t* xrow = xs + ty * 4 * LSTRIDE;
    const uint64_t* wrow = ws + tx * LSTRIDE;
#pragma unroll 4
    for (int kk = 0; kk < KW; kk += 2) {
        ulonglong2 a[4]; ulonglong2 b[8];
#pragma unroll
        for (int i = 0; i < 4; ++i)
            a[i] = *reinterpret_cast<const ulonglong2*>(xrow + i * LSTRIDE + kk);
#pragma unroll
        for (int j = 0; j < 8; ++j)
            b[j] = *reinterpret_cast<const ulonglong2*>(wrow + j * 16 * LSTRIDE + kk);
#pragma unroll
        for (int i = 0; i < 4; ++i)
#pragma unroll
            for (int j = 0; j < 8; ++j)
                acc[i][j] += __builtin_popcountll(a[i].x ^ b[j].x)
                           + __builtin_popcountll(a[i].y ^ b[j].y);
    }
    float bcol[8];
#pragma unroll
    for (int j = 0; j < 8; ++j) bcol[j] = bias[col0 + tx + 16 * j];
#pragma unroll
    for (int i = 0; i < 4; ++i) {
        size_t r = (size_t)(row0 + ty * 4 + i);
#pragma unroll
        for (int j = 0; j < 8; ++j) {
            int c = col0 + tx + 16 * j;
            out[r * OUTF + c] = (float)(INF - 2 * acc[i][j]) + bcol[j];
        }
    }
}
// ============================================================================

extern "C" void kernel_launch(void* const* d_in, const int* in_sizes, int n_in,
                              void* d_out, int out_size, void* d_ws, size_t ws_size,
                              hipStream_t stream) {
    const float* x    = (const float*)d_in[0];
    const float* w    = (const float*)d_in[1];
    const float* bias = (const float*)d_in[2];
    float* out = (float*)d_out;

    const size_t need4 = (size_t)NTOK * KB4 + (size_t)OUTF * KB4;   // 25.2 MB
    const size_t need8 = (size_t)NTOK * KDIM + (size_t)OUTF * KDIM; // 50.3 MB

    if (ws_size >= need4) {
        char* xp = (char*)d_ws;
        char* wp = xp + (size_t)NTOK * KB4;
        const int gx   = NTOK * KDIM / 16;                // 2097152 (16-float tasks)
        const int gtot = gx + OUTF * KDIM / 16;           // 3145728
        pack_fp4<<<2048, 256, 0, stream>>>(x, w, xp, wp, gx, gtot);
        bgemm_fp4<<<512, 512, 0, stream>>>(xp, wp, bias, out);
    } else if (ws_size >= need8) {
        char* xp = (char*)d_ws;
        char* wp = xp + (size_t)NTOK * KDIM;
        const int gx   = NTOK * KDIM / 16;
        const int gtot = gx + OUTF * KDIM / 16;
        pack_i8<<<2048, 256, 0, stream>>>(x, w, xp, wp, gx, gtot);
        bgemm_i8_4ph<<<512, 512, 0, stream>>>(xp, wp, bias, out);
    } else {
        uint64_t* xp = (uint64_t*)d_ws;
        uint64_t* wp = xp + (size_t)NTOK * KW;
        const int nx   = NTOK * KW;
        const int ntot = nx + OUTF * KW;
        pack_both_fb<<<2048, 256, 0, stream>>>(x, w, xp, wp, nx, ntot);
        dim3 grid(OUTF / 128, NTOK / 128);
        bgemm_popc_fb<<<grid, 512, 0, stream>>>(xp, wp, bias, out);
    }
}